// Round 1
// baseline (471.826 us; speedup 1.0000x reference)
//
#include <hip/hip_runtime.h>

// AutoDecoderLayer on MI355X.
// Algebra: with X=embdding, Y=history,
//   G = X^T X  (E x E Gram, shared over heads)
//   scores_h = (Wk_h G Wq_h^T + u_h bq_h^T + bk_h v_h^T + S bk_h bq_h^T)/32
//       u_h = Wk_h xbar, v_h = Wq_h xbar, xbar = colsum(X)
//   A_h = softmax_rows(scores_h)
//   M = sum_h Wv_h^T A_h Wz_h^T ;  d = bz + sum_h (bv_h^T A_h) Wz_h^T
//   O = Y M + d ; LN1 = LN(O)+X ; FN = LN1 Wf^T + bf ; out = LN(FN)+LN1
// ~95 GFLOP total (vs ~490 naive). All GEMMs in NT form for MFMA.
// Workspace requirement: >= 167 MB.

constexpr int EMB = 1024;
constexpr int SEQ = 4096;
constexpr int NH  = 8;

using f32x4  = __attribute__((ext_vector_type(4))) float;
using bf16x8 = __attribute__((ext_vector_type(8))) __bf16;
using us8    = __attribute__((ext_vector_type(8))) unsigned short;

__device__ inline unsigned short f2bf(float x) {
  unsigned int u = __float_as_uint(x);
  u += 0x7FFFu + ((u >> 16) & 1u);   // round-to-nearest-even
  return (unsigned short)(u >> 16);
}
__device__ inline float bf2f(unsigned short h) {
  return __uint_as_float(((unsigned int)h) << 16);
}

// ---------------------------------------------------------------- conversions
__global__ __launch_bounds__(256) void cvt_bf16_k(const float* __restrict__ src,
                                                  unsigned short* __restrict__ dst,
                                                  int n4) {
  int i = blockIdx.x * 256 + threadIdx.x;
  if (i >= n4) return;
  float4 v = ((const float4*)src)[i];
  ushort4 o; o.x = f2bf(v.x); o.y = f2bf(v.y); o.z = f2bf(v.z); o.w = f2bf(v.w);
  ((ushort4*)dst)[i] = o;
}

// dst[z][c][r] = bf16(src[z][r][c]); grid (cols/32, rows/32, z), block 256
__global__ __launch_bounds__(256) void tr_f32_bf16_k(const float* __restrict__ src,
                                                     unsigned short* __restrict__ dst,
                                                     int rows, int cols) {
  __shared__ float t[32][33];
  size_t zoff = (size_t)blockIdx.z * rows * cols;
  int c0 = blockIdx.x * 32, r0 = blockIdx.y * 32;
  int tx = threadIdx.x & 31, ty = threadIdx.x >> 5;
#pragma unroll
  for (int k = 0; k < 4; ++k) {
    int r = ty + k * 8;
    t[r][tx] = src[zoff + (size_t)(r0 + r) * cols + c0 + tx];
  }
  __syncthreads();
#pragma unroll
  for (int k = 0; k < 4; ++k) {
    int r = ty + k * 8;
    dst[zoff + (size_t)(c0 + r) * rows + r0 + tx] = f2bf(t[tx][r]);
  }
}

// dst[z][c][r] = src[z][r][c], bf16
__global__ __launch_bounds__(256) void tr_bf16_k(const unsigned short* __restrict__ src,
                                                 unsigned short* __restrict__ dst,
                                                 int rows, int cols) {
  __shared__ unsigned short t[32][33];
  size_t zoff = (size_t)blockIdx.z * rows * cols;
  int c0 = blockIdx.x * 32, r0 = blockIdx.y * 32;
  int tx = threadIdx.x & 31, ty = threadIdx.x >> 5;
#pragma unroll
  for (int k = 0; k < 4; ++k) {
    int r = ty + k * 8;
    t[r][tx] = src[zoff + (size_t)(r0 + r) * cols + c0 + tx];
  }
  __syncthreads();
#pragma unroll
  for (int k = 0; k < 4; ++k) {
    int r = ty + k * 8;
    dst[zoff + (size_t)(c0 + r) * rows + r0 + tx] = t[tx][r];
  }
}

// ---------------------------------------------------------------- small vecs
__global__ __launch_bounds__(256) void colsum_part_k(const float* __restrict__ X,
                                                     float* __restrict__ part) {
  int e = blockIdx.x * 256 + threadIdx.x;  // grid.x = 4
  int y = blockIdx.y;                      // 32 chunks of 128 rows
  float s = 0.f;
  for (int r = y * 128; r < y * 128 + 128; ++r) s += X[(size_t)r * EMB + e];
  part[y * EMB + e] = s;
}
__global__ __launch_bounds__(256) void colsum_red_k(const float* __restrict__ part,
                                                    float* __restrict__ xbar) {
  int e = blockIdx.x * 256 + threadIdx.x;
  float s = 0.f;
  for (int y = 0; y < 32; ++y) s += part[y * EMB + e];
  xbar[e] = s;
}

// u[h,e'] = Wk[h,e',:].xbar ; v[h,f] = Wq[h,f,:].xbar  (one wave per row)
__global__ __launch_bounds__(256) void uv_k(const float* __restrict__ Wk,
                                            const float* __restrict__ Wq,
                                            const float* __restrict__ xbar,
                                            float* __restrict__ u,
                                            float* __restrict__ v) {
  int gw = blockIdx.x * 4 + (threadIdx.x >> 6);  // 0..2*NH*EMB-1
  int lane = threadIdx.x & 63;
  const float* row;
  float* outp;
  if (gw < NH * EMB) { row = Wk + (size_t)gw * EMB; outp = u + gw; }
  else { int r = gw - NH * EMB; row = Wq + (size_t)r * EMB; outp = v + r; }
  float s = 0.f;
  for (int k = lane; k < EMB; k += 64) s += row[k] * xbar[k];
#pragma unroll
  for (int off = 32; off; off >>= 1) s += __shfl_down(s, off);
  if (lane == 0) *outp = s;
}

// c[h,f] = sum_{e'} AT[h,f,e'] * bv[h,e']   (one wave per (h,f))
__global__ __launch_bounds__(256) void cvec_k(const unsigned short* __restrict__ AT,
                                              const float* __restrict__ bv,
                                              float* __restrict__ c) {
  int gw = blockIdx.x * 4 + (threadIdx.x >> 6);  // 0..NH*EMB-1
  int lane = threadIdx.x & 63;
  int h = gw >> 10;
  const unsigned short* row = AT + (size_t)gw * EMB;
  const float* bvh = bv + h * EMB;
  float s = 0.f;
  for (int k = lane; k < EMB; k += 64) s += bf2f(row[k]) * bvh[k];
#pragma unroll
  for (int off = 32; off; off >>= 1) s += __shfl_down(s, off);
  if (lane == 0) c[gw] = s;
}

// d[g] = bz[g] + sum_{hf} c[hf] * Wz[g, hf]   (one wave per g)
__global__ __launch_bounds__(256) void dvec_k(const float* __restrict__ Wz,
                                              const float* __restrict__ bz,
                                              const float* __restrict__ c,
                                              float* __restrict__ d) {
  int gw = blockIdx.x * 4 + (threadIdx.x >> 6);  // 0..EMB-1
  int lane = threadIdx.x & 63;
  const float* row = Wz + (size_t)gw * (NH * EMB);
  float s = 0.f;
  for (int k = lane; k < NH * EMB; k += 64) s += row[k] * c[k];
#pragma unroll
  for (int off = 32; off; off >>= 1) s += __shfl_down(s, off);
  if (lane == 0) d[gw] = bz[gw] + s;
}

// MT[g][e] = bf16( sum_h Mp[h][e][g] )
__global__ __launch_bounds__(256) void mred_tr_k(const float* __restrict__ Mp,
                                                 unsigned short* __restrict__ MT) {
  __shared__ float t[32][33];
  int g0 = blockIdx.x * 32, e0 = blockIdx.y * 32;
  int tx = threadIdx.x & 31, ty = threadIdx.x >> 5;
#pragma unroll
  for (int k = 0; k < 4; ++k) {
    int e = e0 + ty + k * 8;
    float s = 0.f;
#pragma unroll
    for (int h = 0; h < NH; ++h)
      s += Mp[((size_t)h << 20) + (size_t)e * EMB + g0 + tx];
    t[ty + k * 8][tx] = s;
  }
  __syncthreads();
#pragma unroll
  for (int k = 0; k < 4; ++k) {
    int r = ty + k * 8;
    MT[(size_t)(g0 + r) * EMB + e0 + tx] = f2bf(t[tx][r]);
  }
}

// ---------------------------------------------------------------- softmax / LN
__global__ __launch_bounds__(256) void softmax_k(const float* __restrict__ Sc,
                                                 unsigned short* __restrict__ A) {
  __shared__ float sb[8];
  int row = blockIdx.x, h = blockIdx.y, tid = threadIdx.x;
  const float* x = Sc + ((size_t)h * EMB + row) * EMB;
  unsigned short* out = A + ((size_t)h * EMB + row) * EMB;
  float4 v = ((const float4*)x)[tid];
  float mx = fmaxf(fmaxf(v.x, v.y), fmaxf(v.z, v.w));
  int lane = tid & 63, w = tid >> 6;
#pragma unroll
  for (int off = 32; off; off >>= 1) mx = fmaxf(mx, __shfl_down(mx, off));
  if (lane == 0) sb[w] = mx;
  __syncthreads();
  mx = fmaxf(fmaxf(sb[0], sb[1]), fmaxf(sb[2], sb[3]));
  float e0 = __expf(v.x - mx), e1 = __expf(v.y - mx);
  float e2 = __expf(v.z - mx), e3 = __expf(v.w - mx);
  float sm = e0 + e1 + e2 + e3;
#pragma unroll
  for (int off = 32; off; off >>= 1) sm += __shfl_down(sm, off);
  __syncthreads();
  if (lane == 0) sb[4 + w] = sm;
  __syncthreads();
  float inv = 1.0f / (sb[4] + sb[5] + sb[6] + sb[7]);
  ushort4 o;
  o.x = f2bf(e0 * inv); o.y = f2bf(e1 * inv); o.z = f2bf(e2 * inv); o.w = f2bf(e3 * inv);
  ((ushort4*)out)[tid] = o;
}

__global__ __launch_bounds__(256) void layernorm_k(const float* __restrict__ Xin,
                                                   const float* __restrict__ resid,
                                                   const float* __restrict__ gw,
                                                   const float* __restrict__ bw,
                                                   float* __restrict__ outf,
                                                   unsigned short* __restrict__ outb) {
  __shared__ float sb[16];
  int row = blockIdx.x, tid = threadIdx.x;
  float4 v = ((const float4*)(Xin + (size_t)row * EMB))[tid];
  float s = v.x + v.y + v.z + v.w;
  float q = v.x * v.x + v.y * v.y + v.z * v.z + v.w * v.w;
  int lane = tid & 63, w = tid >> 6;
#pragma unroll
  for (int off = 32; off; off >>= 1) { s += __shfl_down(s, off); q += __shfl_down(q, off); }
  if (lane == 0) { sb[w] = s; sb[8 + w] = q; }
  __syncthreads();
  float mu  = (sb[0] + sb[1] + sb[2] + sb[3]) * (1.0f / EMB);
  float var = (sb[8] + sb[9] + sb[10] + sb[11]) * (1.0f / EMB) - mu * mu;
  float rs = rsqrtf(var + 1e-5f);
  float4 rv = ((const float4*)(resid + (size_t)row * EMB))[tid];
  float4 gv = ((const float4*)gw)[tid];
  float4 bv = ((const float4*)bw)[tid];
  float o0 = (v.x - mu) * rs * gv.x + bv.x + rv.x;
  float o1 = (v.y - mu) * rs * gv.y + bv.y + rv.y;
  float o2 = (v.z - mu) * rs * gv.z + bv.z + rv.z;
  float o3 = (v.w - mu) * rs * gv.w + bv.w + rv.w;
  float4 ov; ov.x = o0; ov.y = o1; ov.z = o2; ov.w = o3;
  ((float4*)(outf + (size_t)row * EMB))[tid] = ov;
  if (outb) {
    ushort4 ob; ob.x = f2bf(o0); ob.y = f2bf(o1); ob.z = f2bf(o2); ob.w = f2bf(o3);
    ((ushort4*)(outb + (size_t)row * EMB))[tid] = ob;
  }
}

// ---------------------------------------------------------------- GEMM (NT)
// C[m,n] = sum_k A[m*lda+k] * B[n*ldb+k], bf16 in, f32 acc.
// MODE 0: f32 store. 1: bf16 store. 2: scores epilogue. 3: +bias[n], f32.
// 128x128 tile, BK=64, 4 waves, 16x16x32 MFMA.
template <int MODE>
__global__ __launch_bounds__(256) void gemm_nt(const unsigned short* __restrict__ A,
                                               const unsigned short* __restrict__ B,
                                               void* __restrict__ Cout,
                                               int K, int lda, int ldb, int ldc,
                                               long long aZ, long long bZ, long long cZ,
                                               const float* __restrict__ e0,
                                               const float* __restrict__ e1,
                                               const float* __restrict__ e2,
                                               const float* __restrict__ e3) {
  const int z = blockIdx.z;
  A += (size_t)z * aZ;
  B += (size_t)z * bZ;
  const int tid = threadIdx.x;
  const int lane = tid & 63, wid = tid >> 6;
  const int wm = wid >> 1, wn = wid & 1;
  const int row0 = blockIdx.x * 128, col0 = blockIdx.y * 128;

  __shared__ __align__(16) unsigned short As[128 * 64];
  __shared__ __align__(16) unsigned short Bs[128 * 64];

  f32x4 acc[4][4] = {};
  const int lrow = lane & 15, kg = lane >> 4;

  for (int k0 = 0; k0 < K; k0 += 64) {
#pragma unroll
    for (int p = 0; p < 4; ++p) {
      int idx = p * 256 + tid;      // 1024 chunks of 8 elems
      int r = idx >> 3;
      int c = (idx & 7) * 8;
      *(us8*)&As[r * 64 + c] = *(const us8*)(A + (size_t)(row0 + r) * lda + k0 + c);
      *(us8*)&Bs[r * 64 + c] = *(const us8*)(B + (size_t)(col0 + r) * ldb + k0 + c);
    }
    __syncthreads();
#pragma unroll
    for (int ks = 0; ks < 2; ++ks) {
      bf16x8 a[4], b[4];
      int koff = ks * 32 + kg * 8;
#pragma unroll
      for (int i = 0; i < 4; ++i)
        a[i] = *(const bf16x8*)&As[(wm * 64 + i * 16 + lrow) * 64 + koff];
#pragma unroll
      for (int j = 0; j < 4; ++j)
        b[j] = *(const bf16x8*)&Bs[(wn * 64 + j * 16 + lrow) * 64 + koff];
#pragma unroll
      for (int i = 0; i < 4; ++i)
#pragma unroll
        for (int j = 0; j < 4; ++j)
          acc[i][j] = __builtin_amdgcn_mfma_f32_16x16x32_bf16(a[i], b[j], acc[i][j], 0, 0, 0);
    }
    __syncthreads();
  }

  const int rb = (lane >> 4) * 4, cc = lane & 15;
#pragma unroll
  for (int i = 0; i < 4; ++i) {
#pragma unroll
    for (int j = 0; j < 4; ++j) {
#pragma unroll
      for (int r = 0; r < 4; ++r) {
        int m = row0 + wm * 64 + i * 16 + rb + r;
        int n = col0 + wn * 64 + j * 16 + cc;
        float val = acc[i][j][r];
        size_t off = (size_t)z * cZ + (size_t)m * ldc + n;
        if (MODE == 0) {
          ((float*)Cout)[off] = val;
        } else if (MODE == 1) {
          ((unsigned short*)Cout)[off] = f2bf(val);
        } else if (MODE == 2) {
          float uu = e0[z * EMB + m], bk = e1[z * EMB + m];
          float bq = e2[z * EMB + n], vv = e3[z * EMB + n];
          ((float*)Cout)[off] = (val + (uu + (float)SEQ * bk) * bq + bk * vv) * (1.0f / 32.0f);
        } else {
          ((float*)Cout)[off] = val + e0[n];
        }
      }
    }
  }
}

// ---------------------------------------------------------------- launch
extern "C" void kernel_launch(void* const* d_in, const int* in_sizes, int n_in,
                              void* d_out, int out_size, void* d_ws, size_t ws_size,
                              hipStream_t stream) {
  const float* history = (const float*)d_in[0];
  const float* emb     = (const float*)d_in[1];
  const float* Wq_w = (const float*)d_in[2];
  const float* Wq_b = (const float*)d_in[3];
  const float* Wk_w = (const float*)d_in[4];
  const float* Wk_b = (const float*)d_in[5];
  const float* Wv_w = (const float*)d_in[6];
  const float* Wv_b = (const float*)d_in[7];
  const float* Wz_w = (const float*)d_in[8];
  const float* Wz_b = (const float*)d_in[9];
  const float* ln1_g = (const float*)d_in[10];
  const float* ln1_b = (const float*)d_in[11];
  const float* Wf_w = (const float*)d_in[12];
  const float* Wf_b = (const float*)d_in[13];
  const float* ln2_g = (const float*)d_in[14];
  const float* ln2_b = (const float*)d_in[15];

  char* ws = (char*)d_ws;
  const size_t MB = 1024ull * 1024ull;
  unsigned short* XT  = (unsigned short*)(ws + 0);        // [E][S] bf16, 8MB ; later LN1bf
  unsigned short* Ybf = (unsigned short*)(ws + 8 * MB);   // [S][E] bf16, 8MB
  unsigned short* Wkb = (unsigned short*)(ws + 16 * MB);  // [H][E][E] bf16, 16MB
  unsigned short* Wqb = (unsigned short*)(ws + 32 * MB);
  unsigned short* WvT = (unsigned short*)(ws + 48 * MB);  // [H][E][E'] transposed
  unsigned short* Wzb = (unsigned short*)(ws + 64 * MB);  // [E][H*E]
  unsigned short* Wfb = (unsigned short*)(ws + 80 * MB);  // [E][E], 2MB
  unsigned short* Gbf = (unsigned short*)(ws + 82 * MB);  // [E][E] bf16 (symmetric), 2MB
  float* xpart = (float*)(ws + 84 * MB);                  // 32*1024 f32
  float* xbar  = (float*)(ws + 84 * MB + 256 * 1024);
  float* ubuf  = (float*)(ws + 84 * MB + 320 * 1024);     // [H][E]
  float* vbuf  = (float*)(ws + 84 * MB + 384 * 1024);
  float* cbuf  = (float*)(ws + 84 * MB + 448 * 1024);     // [H][E]
  float* dbuf  = (float*)(ws + 84 * MB + 512 * 1024);     // [E]
  unsigned short* Tbf = (unsigned short*)(ws + 85 * MB);  // 16MB; later Cbf, later FN f32
  float* Sc  = (float*)(ws + 101 * MB);                   // 32MB scores; later Mp
  unsigned short* Abf = (unsigned short*)(ws + 133 * MB); // 16MB; later O f32
  unsigned short* ATb = (unsigned short*)(ws + 149 * MB); // 16MB; later LN1 f32
  unsigned short* MTb = (unsigned short*)(ws + 165 * MB); // 2MB
  // aliases (lifetimes verified non-overlapping)
  unsigned short* Cbf  = Tbf;
  float* Mp   = Sc;
  float* Obuf = (float*)Abf;
  float* LN1  = (float*)ATb;
  unsigned short* LN1b = XT;
  float* FN   = (float*)Tbf;

  auto cgrid = [](int n4) { return dim3((n4 + 255) / 256); };

  // --- input conversions (f32 -> bf16)
  cvt_bf16_k<<<cgrid(SEQ * EMB / 4), 256, 0, stream>>>(history, Ybf, SEQ * EMB / 4);
  cvt_bf16_k<<<cgrid(NH * EMB * EMB / 4), 256, 0, stream>>>(Wk_w, Wkb, NH * EMB * EMB / 4);
  cvt_bf16_k<<<cgrid(NH * EMB * EMB / 4), 256, 0, stream>>>(Wq_w, Wqb, NH * EMB * EMB / 4);
  cvt_bf16_k<<<cgrid(NH * EMB * EMB / 4), 256, 0, stream>>>(Wz_w, Wzb, NH * EMB * EMB / 4);
  cvt_bf16_k<<<cgrid(EMB * EMB / 4), 256, 0, stream>>>(Wf_w, Wfb, EMB * EMB / 4);
  tr_f32_bf16_k<<<dim3(EMB / 32, SEQ / 32, 1), 256, 0, stream>>>(emb, XT, SEQ, EMB);
  tr_f32_bf16_k<<<dim3(EMB / 32, EMB / 32, NH), 256, 0, stream>>>(Wv_w, WvT, EMB, EMB);

  // --- xbar, u, v
  colsum_part_k<<<dim3(4, 32), 256, 0, stream>>>(emb, xpart);
  colsum_red_k<<<dim3(4), 256, 0, stream>>>(xpart, xbar);
  uv_k<<<dim3(2 * NH * EMB / 4), 256, 0, stream>>>(Wk_w, Wq_w, xbar, ubuf, vbuf);

  // --- G = XT * XT^T (Gram, bf16 out)
  gemm_nt<1><<<dim3(8, 8, 1), 256, 0, stream>>>(XT, XT, Gbf, SEQ, SEQ, SEQ, EMB,
                                                0, 0, 0, nullptr, nullptr, nullptr, nullptr);
  // --- T_h = Wk_h * G   (uses G symmetry for the NT B-operand)
  gemm_nt<1><<<dim3(8, 8, NH), 256, 0, stream>>>(Wkb, Gbf, Tbf, EMB, EMB, EMB, EMB,
                                                 (long long)EMB * EMB, 0, (long long)EMB * EMB,
                                                 nullptr, nullptr, nullptr, nullptr);
  // --- scores_h = T_h * Wq_h^T / 32 + rank-1 bias terms
  gemm_nt<2><<<dim3(8, 8, NH), 256, 0, stream>>>(Tbf, Wqb, Sc, EMB, EMB, EMB, EMB,
                                                 (long long)EMB * EMB, (long long)EMB * EMB,
                                                 (long long)EMB * EMB, ubuf, Wk_b, Wq_b, vbuf);
  // --- A = softmax rows, AT = A^T
  softmax_k<<<dim3(EMB, NH), 256, 0, stream>>>(Sc, Abf);
  tr_bf16_k<<<dim3(EMB / 32, EMB / 32, NH), 256, 0, stream>>>(Abf, ATb, EMB, EMB);
  cvec_k<<<dim3(NH * EMB / 4), 256, 0, stream>>>(ATb, Wv_b, cbuf);
  // --- C_h = WvT_h * AT_h^T  == Wv_h^T A_h
  gemm_nt<1><<<dim3(8, 8, NH), 256, 0, stream>>>(WvT, ATb, Cbf, EMB, EMB, EMB, EMB,
                                                 (long long)EMB * EMB, (long long)EMB * EMB,
                                                 (long long)EMB * EMB,
                                                 nullptr, nullptr, nullptr, nullptr);
  // --- Mp_h = C_h * Wz_h^T  (f32)
  gemm_nt<0><<<dim3(8, 8, NH), 256, 0, stream>>>(Cbf, Wzb, Mp, EMB, EMB, NH * EMB, EMB,
                                                 (long long)EMB * EMB, (long long)EMB,
                                                 (long long)EMB * EMB,
                                                 nullptr, nullptr, nullptr, nullptr);
  // --- M = sum_h Mp_h, transposed+bf16 ; d vector
  mred_tr_k<<<dim3(EMB / 32, EMB / 32), 256, 0, stream>>>(Mp, MTb);
  dvec_k<<<dim3(EMB / 4), 256, 0, stream>>>(Wz_w, Wz_b, cbuf, dbuf);
  // --- O = Y * M + d
  gemm_nt<3><<<dim3(SEQ / 128, 8, 1), 256, 0, stream>>>(Ybf, MTb, Obuf, EMB, EMB, EMB, EMB,
                                                        0, 0, 0, dbuf, nullptr, nullptr, nullptr);
  // --- LN1 = LN(O)+emb (f32 + bf16 copies)
  layernorm_k<<<dim3(SEQ), 256, 0, stream>>>(Obuf, emb, ln1_g, ln1_b, LN1, LN1b);
  // --- FN = LN1 * Wf^T + bf
  gemm_nt<3><<<dim3(SEQ / 128, 8, 1), 256, 0, stream>>>(LN1b, Wfb, FN, EMB, EMB, EMB, EMB,
                                                        0, 0, 0, Wf_b, nullptr, nullptr, nullptr);
  // --- out = LN(FN)+LN1
  layernorm_k<<<dim3(SEQ), 256, 0, stream>>>(FN, LN1, ln2_g, ln2_b, (float*)d_out, nullptr);
}

// Round 2
// 409.065 us; speedup vs baseline: 1.1534x; 1.1534x over previous
//
#include <hip/hip_runtime.h>

// AutoDecoderLayer on MI355X.
// Algebra: with X=embdding, Y=history,
//   G = X^T X  (E x E Gram, shared over heads)
//   scores_h = (Wk_h G Wq_h^T + u_h bq_h^T + bk_h v_h^T + S bk_h bq_h^T)/32
//   A_h = softmax_rows(scores_h)
//   M = sum_h Wv_h^T A_h Wz_h^T ;  d = bz + sum_h (bv_h^T A_h) Wz_h^T
//   O = Y M + d ; LN1 = LN(O)+X ; FN = LN1 Wf^T + bf ; out = LN(FN)+LN1
// ~95 GFLOP total. R1: global_load_lds staging + split-K Gram.

constexpr int EMB = 1024;
constexpr int SEQ = 4096;
constexpr int NH  = 8;

using f32x4  = __attribute__((ext_vector_type(4))) float;
using bf16x8 = __attribute__((ext_vector_type(8))) __bf16;
using us8    = __attribute__((ext_vector_type(8))) unsigned short;

#define GLOAD_LDS16(g, l) __builtin_amdgcn_global_load_lds(                 \
    (const __attribute__((address_space(1))) void*)(g),                     \
    (__attribute__((address_space(3))) void*)(l), 16, 0, 0)

__device__ inline unsigned short f2bf(float x) {
  unsigned int u = __float_as_uint(x);
  u += 0x7FFFu + ((u >> 16) & 1u);   // round-to-nearest-even
  return (unsigned short)(u >> 16);
}
__device__ inline float bf2f(unsigned short h) {
  return __uint_as_float(((unsigned int)h) << 16);
}

// ---------------------------------------------------------------- conversions
__global__ __launch_bounds__(256) void cvt_bf16_k(const float* __restrict__ src,
                                                  unsigned short* __restrict__ dst,
                                                  int n4) {
  int i = blockIdx.x * 256 + threadIdx.x;
  if (i >= n4) return;
  float4 v = ((const float4*)src)[i];
  ushort4 o; o.x = f2bf(v.x); o.y = f2bf(v.y); o.z = f2bf(v.z); o.w = f2bf(v.w);
  ((ushort4*)dst)[i] = o;
}

// dst[z][c][r] = bf16(src[z][r][c]); grid (cols/32, rows/32, z), block 256
__global__ __launch_bounds__(256) void tr_f32_bf16_k(const float* __restrict__ src,
                                                     unsigned short* __restrict__ dst,
                                                     int rows, int cols) {
  __shared__ float t[32][33];
  size_t zoff = (size_t)blockIdx.z * rows * cols;
  int c0 = blockIdx.x * 32, r0 = blockIdx.y * 32;
  int tx = threadIdx.x & 31, ty = threadIdx.x >> 5;
#pragma unroll
  for (int k = 0; k < 4; ++k) {
    int r = ty + k * 8;
    t[r][tx] = src[zoff + (size_t)(r0 + r) * cols + c0 + tx];
  }
  __syncthreads();
#pragma unroll
  for (int k = 0; k < 4; ++k) {
    int r = ty + k * 8;
    dst[zoff + (size_t)(c0 + r) * rows + r0 + tx] = f2bf(t[tx][r]);
  }
}

// dst[z][c][r] = src[z][r][c], bf16
__global__ __launch_bounds__(256) void tr_bf16_k(const unsigned short* __restrict__ src,
                                                 unsigned short* __restrict__ dst,
                                                 int rows, int cols) {
  __shared__ unsigned short t[32][33];
  size_t zoff = (size_t)blockIdx.z * rows * cols;
  int c0 = blockIdx.x * 32, r0 = blockIdx.y * 32;
  int tx = threadIdx.x & 31, ty = threadIdx.x >> 5;
#pragma unroll
  for (int k = 0; k < 4; ++k) {
    int r = ty + k * 8;
    t[r][tx] = src[zoff + (size_t)(r0 + r) * cols + c0 + tx];
  }
  __syncthreads();
#pragma unroll
  for (int k = 0; k < 4; ++k) {
    int r = ty + k * 8;
    dst[zoff + (size_t)(c0 + r) * rows + r0 + tx] = t[tx][r];
  }
}

// ---------------------------------------------------------------- small vecs
__global__ __launch_bounds__(256) void colsum_part_k(const float* __restrict__ X,
                                                     float* __restrict__ part) {
  int e = blockIdx.x * 256 + threadIdx.x;  // grid.x = 4
  int y = blockIdx.y;                      // 32 chunks of 128 rows
  float s = 0.f;
  for (int r = y * 128; r < y * 128 + 128; ++r) s += X[(size_t)r * EMB + e];
  part[y * EMB + e] = s;
}
__global__ __launch_bounds__(256) void colsum_red_k(const float* __restrict__ part,
                                                    float* __restrict__ xbar) {
  int e = blockIdx.x * 256 + threadIdx.x;
  float s = 0.f;
  for (int y = 0; y < 32; ++y) s += part[y * EMB + e];
  xbar[e] = s;
}

// u[h,e'] = Wk[h,e',:].xbar ; v[h,f] = Wq[h,f,:].xbar  (one wave per row)
__global__ __launch_bounds__(256) void uv_k(const float* __restrict__ Wk,
                                            const float* __restrict__ Wq,
                                            const float* __restrict__ xbar,
                                            float* __restrict__ u,
                                            float* __restrict__ v) {
  int gw = blockIdx.x * 4 + (threadIdx.x >> 6);  // 0..2*NH*EMB-1
  int lane = threadIdx.x & 63;
  const float* row;
  float* outp;
  if (gw < NH * EMB) { row = Wk + (size_t)gw * EMB; outp = u + gw; }
  else { int r = gw - NH * EMB; row = Wq + (size_t)r * EMB; outp = v + r; }
  float s = 0.f;
  for (int k = lane; k < EMB; k += 64) s += row[k] * xbar[k];
#pragma unroll
  for (int off = 32; off; off >>= 1) s += __shfl_down(s, off);
  if (lane == 0) *outp = s;
}

// c[h,f] = sum_{e'} AT[h,f,e'] * bv[h,e']   (one wave per (h,f))
__global__ __launch_bounds__(256) void cvec_k(const unsigned short* __restrict__ AT,
                                              const float* __restrict__ bv,
                                              float* __restrict__ c) {
  int gw = blockIdx.x * 4 + (threadIdx.x >> 6);  // 0..NH*EMB-1
  int lane = threadIdx.x & 63;
  int h = gw >> 10;
  const unsigned short* row = AT + (size_t)gw * EMB;
  const float* bvh = bv + h * EMB;
  float s = 0.f;
  for (int k = lane; k < EMB; k += 64) s += bf2f(row[k]) * bvh[k];
#pragma unroll
  for (int off = 32; off; off >>= 1) s += __shfl_down(s, off);
  if (lane == 0) c[gw] = s;
}

// d[g] = bz[g] + sum_{hf} c[hf] * Wz[g, hf]   (one wave per g)
__global__ __launch_bounds__(256) void dvec_k(const float* __restrict__ Wz,
                                              const float* __restrict__ bz,
                                              const float* __restrict__ c,
                                              float* __restrict__ d) {
  int gw = blockIdx.x * 4 + (threadIdx.x >> 6);  // 0..EMB-1
  int lane = threadIdx.x & 63;
  const float* row = Wz + (size_t)gw * (NH * EMB);
  float s = 0.f;
  for (int k = lane; k < NH * EMB; k += 64) s += row[k] * c[k];
#pragma unroll
  for (int off = 32; off; off >>= 1) s += __shfl_down(s, off);
  if (lane == 0) d[gw] = bz[gw] + s;
}

// MT[g][e] = bf16( sum_h Mp[h][e][g] )
__global__ __launch_bounds__(256) void mred_tr_k(const float* __restrict__ Mp,
                                                 unsigned short* __restrict__ MT) {
  __shared__ float t[32][33];
  int g0 = blockIdx.x * 32, e0 = blockIdx.y * 32;
  int tx = threadIdx.x & 31, ty = threadIdx.x >> 5;
#pragma unroll
  for (int k = 0; k < 4; ++k) {
    int e = e0 + ty + k * 8;
    float s = 0.f;
#pragma unroll
    for (int h = 0; h < NH; ++h)
      s += Mp[((size_t)h << 20) + (size_t)e * EMB + g0 + tx];
    t[ty + k * 8][tx] = s;
  }
  __syncthreads();
#pragma unroll
  for (int k = 0; k < 4; ++k) {
    int r = ty + k * 8;
    MT[(size_t)(g0 + r) * EMB + e0 + tx] = f2bf(t[tx][r]);
  }
}

// Gbf[i] = bf16( sum_z Gp[z][i] ), float4-granular
__global__ __launch_bounds__(256) void gram_red_k(const float* __restrict__ Gp,
                                                  unsigned short* __restrict__ Gbf) {
  int i = blockIdx.x * 256 + threadIdx.x;  // grid = EMB*EMB/4/256
  float4 s = ((const float4*)Gp)[i];
#pragma unroll
  for (int z = 1; z < 8; ++z) {
    float4 v = ((const float4*)(Gp + (size_t)z * EMB * EMB))[i];
    s.x += v.x; s.y += v.y; s.z += v.z; s.w += v.w;
  }
  ushort4 o; o.x = f2bf(s.x); o.y = f2bf(s.y); o.z = f2bf(s.z); o.w = f2bf(s.w);
  ((ushort4*)Gbf)[i] = o;
}

// ---------------------------------------------------------------- softmax / LN
__global__ __launch_bounds__(256) void softmax_k(const float* __restrict__ Sc,
                                                 unsigned short* __restrict__ A) {
  __shared__ float sb[8];
  int row = blockIdx.x, h = blockIdx.y, tid = threadIdx.x;
  const float* x = Sc + ((size_t)h * EMB + row) * EMB;
  unsigned short* out = A + ((size_t)h * EMB + row) * EMB;
  float4 v = ((const float4*)x)[tid];
  float mx = fmaxf(fmaxf(v.x, v.y), fmaxf(v.z, v.w));
  int lane = tid & 63, w = tid >> 6;
#pragma unroll
  for (int off = 32; off; off >>= 1) mx = fmaxf(mx, __shfl_down(mx, off));
  if (lane == 0) sb[w] = mx;
  __syncthreads();
  mx = fmaxf(fmaxf(sb[0], sb[1]), fmaxf(sb[2], sb[3]));
  float e0 = __expf(v.x - mx), e1 = __expf(v.y - mx);
  float e2 = __expf(v.z - mx), e3 = __expf(v.w - mx);
  float sm = e0 + e1 + e2 + e3;
#pragma unroll
  for (int off = 32; off; off >>= 1) sm += __shfl_down(sm, off);
  __syncthreads();
  if (lane == 0) sb[4 + w] = sm;
  __syncthreads();
  float inv = 1.0f / (sb[4] + sb[5] + sb[6] + sb[7]);
  ushort4 o;
  o.x = f2bf(e0 * inv); o.y = f2bf(e1 * inv); o.z = f2bf(e2 * inv); o.w = f2bf(e3 * inv);
  ((ushort4*)out)[tid] = o;
}

__global__ __launch_bounds__(256) void layernorm_k(const float* __restrict__ Xin,
                                                   const float* __restrict__ resid,
                                                   const float* __restrict__ gw,
                                                   const float* __restrict__ bw,
                                                   float* __restrict__ outf,
                                                   unsigned short* __restrict__ outb) {
  __shared__ float sb[16];
  int row = blockIdx.x, tid = threadIdx.x;
  float4 v = ((const float4*)(Xin + (size_t)row * EMB))[tid];
  float s = v.x + v.y + v.z + v.w;
  float q = v.x * v.x + v.y * v.y + v.z * v.z + v.w * v.w;
  int lane = tid & 63, w = tid >> 6;
#pragma unroll
  for (int off = 32; off; off >>= 1) { s += __shfl_down(s, off); q += __shfl_down(q, off); }
  if (lane == 0) { sb[w] = s; sb[8 + w] = q; }
  __syncthreads();
  float mu  = (sb[0] + sb[1] + sb[2] + sb[3]) * (1.0f / EMB);
  float var = (sb[8] + sb[9] + sb[10] + sb[11]) * (1.0f / EMB) - mu * mu;
  float rs = rsqrtf(var + 1e-5f);
  float4 rv = ((const float4*)(resid + (size_t)row * EMB))[tid];
  float4 gv = ((const float4*)gw)[tid];
  float4 bv = ((const float4*)bw)[tid];
  float o0 = (v.x - mu) * rs * gv.x + bv.x + rv.x;
  float o1 = (v.y - mu) * rs * gv.y + bv.y + rv.y;
  float o2 = (v.z - mu) * rs * gv.z + bv.z + rv.z;
  float o3 = (v.w - mu) * rs * gv.w + bv.w + rv.w;
  float4 ov; ov.x = o0; ov.y = o1; ov.z = o2; ov.w = o3;
  ((float4*)(outf + (size_t)row * EMB))[tid] = ov;
  if (outb) {
    ushort4 ob; ob.x = f2bf(o0); ob.y = f2bf(o1); ob.z = f2bf(o2); ob.w = f2bf(o3);
    ((ushort4*)(outb + (size_t)row * EMB))[tid] = ob;
  }
}

// ---------------------------------------------------------------- GEMM (NT)
// C[m,n] = sum_k A[m*lda+k] * B[n*ldb+k], bf16 in, f32 acc.
// MODE 0: f32 store. 1: bf16 store. 2: scores epilogue. 3: +bias[n], f32.
// 128x128 tile, BK=64, 4 waves, 16x16x32 MFMA, global_load_lds staging.
template <int MODE>
__global__ __launch_bounds__(256) void gemm_nt(const unsigned short* __restrict__ A,
                                               const unsigned short* __restrict__ B,
                                               void* __restrict__ Cout,
                                               int K, int lda, int ldb, int ldc,
                                               long long aZ, long long bZ, long long cZ,
                                               const float* __restrict__ e0,
                                               const float* __restrict__ e1,
                                               const float* __restrict__ e2,
                                               const float* __restrict__ e3) {
  const int z = blockIdx.z;
  A += (size_t)z * aZ;
  B += (size_t)z * bZ;
  const int tid = threadIdx.x;
  const int lane = tid & 63, wid = tid >> 6;
  const int wm = wid >> 1, wn = wid & 1;
  const int row0 = blockIdx.x * 128, col0 = blockIdx.y * 128;

  __shared__ __align__(16) unsigned short As[128 * 64];
  __shared__ __align__(16) unsigned short Bs[128 * 64];

  f32x4 acc[4][4] = {};
  const int lrow = lane & 15, kg = lane >> 4;
  const int lr = lane >> 3;        // row within an 8-row chunk
  const int lc = (lane & 7) * 8;   // elem col within 64

  for (int k0 = 0; k0 < K; k0 += 64) {
    // stage As/Bs [128][64] via direct global->LDS (1 KiB per instruction).
    // LDS dest is wave-uniform chunk base; lane l lands at base + l*16B,
    // which equals row (l>>3), col (l&7)*8 of the chunk - matches src addr.
#pragma unroll
    for (int c = 0; c < 4; ++c) {
      int chunk = wid * 4 + c;           // 0..15, 8 rows each
      int r = chunk * 8 + lr;
      GLOAD_LDS16(A + (size_t)(row0 + r) * lda + k0 + lc, &As[chunk * 512]);
      GLOAD_LDS16(B + (size_t)(col0 + r) * ldb + k0 + lc, &Bs[chunk * 512]);
    }
    __syncthreads();
#pragma unroll
    for (int ks = 0; ks < 2; ++ks) {
      bf16x8 a[4], b[4];
      int koff = ks * 32 + kg * 8;
#pragma unroll
      for (int i = 0; i < 4; ++i)
        a[i] = *(const bf16x8*)&As[(wm * 64 + i * 16 + lrow) * 64 + koff];
#pragma unroll
      for (int j = 0; j < 4; ++j)
        b[j] = *(const bf16x8*)&Bs[(wn * 64 + j * 16 + lrow) * 64 + koff];
#pragma unroll
      for (int i = 0; i < 4; ++i)
#pragma unroll
        for (int j = 0; j < 4; ++j)
          acc[i][j] = __builtin_amdgcn_mfma_f32_16x16x32_bf16(a[i], b[j], acc[i][j], 0, 0, 0);
    }
    __syncthreads();
  }

  const int rb = (lane >> 4) * 4, cc = lane & 15;
#pragma unroll
  for (int i = 0; i < 4; ++i) {
#pragma unroll
    for (int j = 0; j < 4; ++j) {
#pragma unroll
      for (int r = 0; r < 4; ++r) {
        int m = row0 + wm * 64 + i * 16 + rb + r;
        int n = col0 + wn * 64 + j * 16 + cc;
        float val = acc[i][j][r];
        size_t off = (size_t)z * cZ + (size_t)m * ldc + n;
        if (MODE == 0) {
          ((float*)Cout)[off] = val;
        } else if (MODE == 1) {
          ((unsigned short*)Cout)[off] = f2bf(val);
        } else if (MODE == 2) {
          float uu = e0[z * EMB + m], bk = e1[z * EMB + m];
          float bq = e2[z * EMB + n], vv = e3[z * EMB + n];
          ((float*)Cout)[off] = (val + (uu + (float)SEQ * bk) * bq + bk * vv) * (1.0f / 32.0f);
        } else {
          ((float*)Cout)[off] = val + e0[n];
        }
      }
    }
  }
}

// ---------------------------------------------------------------- launch
extern "C" void kernel_launch(void* const* d_in, const int* in_sizes, int n_in,
                              void* d_out, int out_size, void* d_ws, size_t ws_size,
                              hipStream_t stream) {
  const float* history = (const float*)d_in[0];
  const float* emb     = (const float*)d_in[1];
  const float* Wq_w = (const float*)d_in[2];
  const float* Wq_b = (const float*)d_in[3];
  const float* Wk_w = (const float*)d_in[4];
  const float* Wk_b = (const float*)d_in[5];
  const float* Wv_w = (const float*)d_in[6];
  const float* Wv_b = (const float*)d_in[7];
  const float* Wz_w = (const float*)d_in[8];
  const float* Wz_b = (const float*)d_in[9];
  const float* ln1_g = (const float*)d_in[10];
  const float* ln1_b = (const float*)d_in[11];
  const float* Wf_w = (const float*)d_in[12];
  const float* Wf_b = (const float*)d_in[13];
  const float* ln2_g = (const float*)d_in[14];
  const float* ln2_b = (const float*)d_in[15];

  char* ws = (char*)d_ws;
  const size_t MB = 1024ull * 1024ull;
  unsigned short* XT  = (unsigned short*)(ws + 0);        // [E][S] bf16, 8MB ; later LN1bf
  unsigned short* Ybf = (unsigned short*)(ws + 8 * MB);   // [S][E] bf16, 8MB
  unsigned short* Wkb = (unsigned short*)(ws + 16 * MB);  // [H][E][E] bf16, 16MB
  unsigned short* Wqb = (unsigned short*)(ws + 32 * MB);
  unsigned short* WvT = (unsigned short*)(ws + 48 * MB);  // [H][E][E'] transposed
  unsigned short* Wzb = (unsigned short*)(ws + 64 * MB);  // [E][H*E]
  unsigned short* Wfb = (unsigned short*)(ws + 80 * MB);  // [E][E], 2MB
  unsigned short* Gbf = (unsigned short*)(ws + 82 * MB);  // [E][E] bf16 (symmetric), 2MB
  float* xpart = (float*)(ws + 84 * MB);                  // 32*1024 f32
  float* xbar  = (float*)(ws + 84 * MB + 256 * 1024);
  float* ubuf  = (float*)(ws + 84 * MB + 320 * 1024);     // [H][E]
  float* vbuf  = (float*)(ws + 84 * MB + 384 * 1024);
  float* cbuf  = (float*)(ws + 84 * MB + 448 * 1024);     // [H][E]
  float* dbuf  = (float*)(ws + 84 * MB + 512 * 1024);     // [E]
  unsigned short* Tbf = (unsigned short*)(ws + 85 * MB);  // 16MB; later Cbf, later FN f32
  float* Sc  = (float*)(ws + 101 * MB);                   // 32MB: Gram partials, scores, Mp
  unsigned short* Abf = (unsigned short*)(ws + 133 * MB); // 16MB; later O f32
  unsigned short* ATb = (unsigned short*)(ws + 149 * MB); // 16MB; later LN1 f32
  unsigned short* MTb = (unsigned short*)(ws + 165 * MB); // 2MB
  // aliases (lifetimes verified non-overlapping)
  float* Gp   = Sc;     // [8][E][E] split-K Gram partials (before scores)
  unsigned short* Cbf  = Tbf;
  float* Mp   = Sc;
  float* Obuf = (float*)Abf;
  float* LN1  = (float*)ATb;
  unsigned short* LN1b = XT;
  float* FN   = (float*)Tbf;

  auto cgrid = [](int n4) { return dim3((n4 + 255) / 256); };

  // --- input conversions (f32 -> bf16)
  cvt_bf16_k<<<cgrid(SEQ * EMB / 4), 256, 0, stream>>>(history, Ybf, SEQ * EMB / 4);
  cvt_bf16_k<<<cgrid(NH * EMB * EMB / 4), 256, 0, stream>>>(Wk_w, Wkb, NH * EMB * EMB / 4);
  cvt_bf16_k<<<cgrid(NH * EMB * EMB / 4), 256, 0, stream>>>(Wq_w, Wqb, NH * EMB * EMB / 4);
  cvt_bf16_k<<<cgrid(NH * EMB * EMB / 4), 256, 0, stream>>>(Wz_w, Wzb, NH * EMB * EMB / 4);
  cvt_bf16_k<<<cgrid(EMB * EMB / 4), 256, 0, stream>>>(Wf_w, Wfb, EMB * EMB / 4);
  tr_f32_bf16_k<<<dim3(EMB / 32, SEQ / 32, 1), 256, 0, stream>>>(emb, XT, SEQ, EMB);
  tr_f32_bf16_k<<<dim3(EMB / 32, EMB / 32, NH), 256, 0, stream>>>(Wv_w, WvT, EMB, EMB);

  // --- xbar, u, v
  colsum_part_k<<<dim3(4, 32), 256, 0, stream>>>(emb, xpart);
  colsum_red_k<<<dim3(4), 256, 0, stream>>>(xpart, xbar);
  uv_k<<<dim3(2 * NH * EMB / 4), 256, 0, stream>>>(Wk_w, Wq_w, xbar, ubuf, vbuf);

  // --- G = XT * XT^T, split-K over z (8 x K=512) -> f32 partials -> bf16
  gemm_nt<0><<<dim3(8, 8, 8), 256, 0, stream>>>(XT, XT, Gp, 512, SEQ, SEQ, EMB,
                                                512, 512, (long long)EMB * EMB,
                                                nullptr, nullptr, nullptr, nullptr);
  gram_red_k<<<cgrid(EMB * EMB / 4), 256, 0, stream>>>(Gp, Gbf);
  // --- T_h = Wk_h * G   (uses G symmetry for the NT B-operand)
  gemm_nt<1><<<dim3(8, 8, NH), 256, 0, stream>>>(Wkb, Gbf, Tbf, EMB, EMB, EMB, EMB,
                                                 (long long)EMB * EMB, 0, (long long)EMB * EMB,
                                                 nullptr, nullptr, nullptr, nullptr);
  // --- scores_h = T_h * Wq_h^T / 32 + rank-1 bias terms
  gemm_nt<2><<<dim3(8, 8, NH), 256, 0, stream>>>(Tbf, Wqb, Sc, EMB, EMB, EMB, EMB,
                                                 (long long)EMB * EMB, (long long)EMB * EMB,
                                                 (long long)EMB * EMB, ubuf, Wk_b, Wq_b, vbuf);
  // --- A = softmax rows, AT = A^T
  softmax_k<<<dim3(EMB, NH), 256, 0, stream>>>(Sc, Abf);
  tr_bf16_k<<<dim3(EMB / 32, EMB / 32, NH), 256, 0, stream>>>(Abf, ATb, EMB, EMB);
  cvec_k<<<dim3(NH * EMB / 4), 256, 0, stream>>>(ATb, Wv_b, cbuf);
  // --- C_h = WvT_h * AT_h^T  == Wv_h^T A_h
  gemm_nt<1><<<dim3(8, 8, NH), 256, 0, stream>>>(WvT, ATb, Cbf, EMB, EMB, EMB, EMB,
                                                 (long long)EMB * EMB, (long long)EMB * EMB,
                                                 (long long)EMB * EMB,
                                                 nullptr, nullptr, nullptr, nullptr);
  // --- Mp_h = C_h * Wz_h^T  (f32)
  gemm_nt<0><<<dim3(8, 8, NH), 256, 0, stream>>>(Cbf, Wzb, Mp, EMB, EMB, NH * EMB, EMB,
                                                 (long long)EMB * EMB, (long long)EMB,
                                                 (long long)EMB * EMB,
                                                 nullptr, nullptr, nullptr, nullptr);
  // --- M = sum_h Mp_h, transposed+bf16 ; d vector
  mred_tr_k<<<dim3(EMB / 32, EMB / 32), 256, 0, stream>>>(Mp, MTb);
  dvec_k<<<dim3(EMB / 4), 256, 0, stream>>>(Wz_w, Wz_b, cbuf, dbuf);
  // --- O = Y * M + d
  gemm_nt<3><<<dim3(SEQ / 128, 8, 1), 256, 0, stream>>>(Ybf, MTb, Obuf, EMB, EMB, EMB, EMB,
                                                        0, 0, 0, dbuf, nullptr, nullptr, nullptr);
  // --- LN1 = LN(O)+emb (f32 + bf16 copies)
  layernorm_k<<<dim3(SEQ), 256, 0, stream>>>(Obuf, emb, ln1_g, ln1_b, LN1, LN1b);
  // --- FN = LN1 * Wf^T + bf
  gemm_nt<3><<<dim3(SEQ / 128, 8, 1), 256, 0, stream>>>(LN1b, Wfb, FN, EMB, EMB, EMB, EMB,
                                                        0, 0, 0, Wf_b, nullptr, nullptr, nullptr);
  // --- out = LN(FN)+LN1
  layernorm_k<<<dim3(SEQ), 256, 0, stream>>>(FN, LN1, ln2_g, ln2_b, (float*)d_out, nullptr);
}

// Round 3
// 335.481 us; speedup vs baseline: 1.4064x; 1.2193x over previous
//
#include <hip/hip_runtime.h>

// AutoDecoderLayer on MI355X.
// Algebra: with X=embdding, Y=history,
//   G = X^T X  (E x E Gram, shared over heads)
//   scores_h = (Wk_h G Wq_h^T + u_h bq_h^T + bk_h v_h^T + S bk_h bq_h^T)/32
//   A_h = softmax_rows(scores_h)
//   M = sum_h Wv_h^T A_h Wz_h^T ;  d = bz + sum_h (bv_h^T A_h) Wz_h^T
//   O = Y M + d ; LN1 = LN(O)+X ; FN = LN1 Wf^T + bf ; out = LN(FN)+LN1
// ~95 GFLOP total. R1: global_load_lds + split-K Gram. R2: dvec parallelism,
// uv fused into Wk/Wq conversion.

constexpr int EMB = 1024;
constexpr int SEQ = 4096;
constexpr int NH  = 8;

using f32x4  = __attribute__((ext_vector_type(4))) float;
using bf16x8 = __attribute__((ext_vector_type(8))) __bf16;
using us8    = __attribute__((ext_vector_type(8))) unsigned short;

#define GLOAD_LDS16(g, l) __builtin_amdgcn_global_load_lds(                 \
    (const __attribute__((address_space(1))) void*)(g),                     \
    (__attribute__((address_space(3))) void*)(l), 16, 0, 0)

__device__ inline unsigned short f2bf(float x) {
  unsigned int u = __float_as_uint(x);
  u += 0x7FFFu + ((u >> 16) & 1u);   // round-to-nearest-even
  return (unsigned short)(u >> 16);
}
__device__ inline float bf2f(unsigned short h) {
  return __uint_as_float(((unsigned int)h) << 16);
}

// ---------------------------------------------------------------- conversions
__global__ __launch_bounds__(256) void cvt_bf16_k(const float* __restrict__ src,
                                                  unsigned short* __restrict__ dst,
                                                  int n4) {
  int i = blockIdx.x * 256 + threadIdx.x;
  if (i >= n4) return;
  float4 v = ((const float4*)src)[i];
  ushort4 o; o.x = f2bf(v.x); o.y = f2bf(v.y); o.z = f2bf(v.z); o.w = f2bf(v.w);
  ((ushort4*)dst)[i] = o;
}

// convert one 1024-elem row to bf16 AND dot it with xbar (one block per row)
__global__ __launch_bounds__(256) void cvt_dot_k(const float* __restrict__ src,
                                                 unsigned short* __restrict__ dst,
                                                 const float* __restrict__ xbar,
                                                 float* __restrict__ dotout) {
  __shared__ float sb[4];
  int row = blockIdx.x, tid = threadIdx.x;
  float4 v  = ((const float4*)(src + (size_t)row * EMB))[tid];
  float4 xb = ((const float4*)xbar)[tid];
  ushort4 o; o.x = f2bf(v.x); o.y = f2bf(v.y); o.z = f2bf(v.z); o.w = f2bf(v.w);
  ((ushort4*)(dst + (size_t)row * EMB))[tid] = o;
  float s = v.x * xb.x + v.y * xb.y + v.z * xb.z + v.w * xb.w;
  int lane = tid & 63, w = tid >> 6;
#pragma unroll
  for (int off = 32; off; off >>= 1) s += __shfl_down(s, off);
  if (lane == 0) sb[w] = s;
  __syncthreads();
  if (tid == 0) dotout[row] = sb[0] + sb[1] + sb[2] + sb[3];
}

// dst[z][c][r] = bf16(src[z][r][c]); grid (cols/32, rows/32, z), block 256
__global__ __launch_bounds__(256) void tr_f32_bf16_k(const float* __restrict__ src,
                                                     unsigned short* __restrict__ dst,
                                                     int rows, int cols) {
  __shared__ float t[32][33];
  size_t zoff = (size_t)blockIdx.z * rows * cols;
  int c0 = blockIdx.x * 32, r0 = blockIdx.y * 32;
  int tx = threadIdx.x & 31, ty = threadIdx.x >> 5;
#pragma unroll
  for (int k = 0; k < 4; ++k) {
    int r = ty + k * 8;
    t[r][tx] = src[zoff + (size_t)(r0 + r) * cols + c0 + tx];
  }
  __syncthreads();
#pragma unroll
  for (int k = 0; k < 4; ++k) {
    int r = ty + k * 8;
    dst[zoff + (size_t)(c0 + r) * rows + r0 + tx] = f2bf(t[tx][r]);
  }
}

// dst[z][c][r] = src[z][r][c], bf16
__global__ __launch_bounds__(256) void tr_bf16_k(const unsigned short* __restrict__ src,
                                                 unsigned short* __restrict__ dst,
                                                 int rows, int cols) {
  __shared__ unsigned short t[32][33];
  size_t zoff = (size_t)blockIdx.z * rows * cols;
  int c0 = blockIdx.x * 32, r0 = blockIdx.y * 32;
  int tx = threadIdx.x & 31, ty = threadIdx.x >> 5;
#pragma unroll
  for (int k = 0; k < 4; ++k) {
    int r = ty + k * 8;
    t[r][tx] = src[zoff + (size_t)(r0 + r) * cols + c0 + tx];
  }
  __syncthreads();
#pragma unroll
  for (int k = 0; k < 4; ++k) {
    int r = ty + k * 8;
    dst[zoff + (size_t)(c0 + r) * rows + r0 + tx] = t[tx][r];
  }
}

// ---------------------------------------------------------------- small vecs
__global__ __launch_bounds__(256) void colsum_part_k(const float* __restrict__ X,
                                                     float* __restrict__ part) {
  int e = blockIdx.x * 256 + threadIdx.x;  // grid.x = 4
  int y = blockIdx.y;                      // 32 chunks of 128 rows
  float s = 0.f;
  for (int r = y * 128; r < y * 128 + 128; ++r) s += X[(size_t)r * EMB + e];
  part[y * EMB + e] = s;
}
__global__ __launch_bounds__(256) void colsum_red_k(const float* __restrict__ part,
                                                    float* __restrict__ xbar) {
  int e = blockIdx.x * 256 + threadIdx.x;
  float s = 0.f;
  for (int y = 0; y < 32; ++y) s += part[y * EMB + e];
  xbar[e] = s;
}

// c[h,f] = sum_{e'} AT[h,f,e'] * bv[h,e']   (one wave per (h,f))
__global__ __launch_bounds__(256) void cvec_k(const unsigned short* __restrict__ AT,
                                              const float* __restrict__ bv,
                                              float* __restrict__ c) {
  int gw = blockIdx.x * 4 + (threadIdx.x >> 6);  // 0..NH*EMB-1
  int lane = threadIdx.x & 63;
  int h = gw >> 10;
  const unsigned short* row = AT + (size_t)gw * EMB;
  const float* bvh = bv + h * EMB;
  float s = 0.f;
  for (int k = lane; k < EMB; k += 64) s += bf2f(row[k]) * bvh[k];
#pragma unroll
  for (int off = 32; off; off >>= 1) s += __shfl_down(s, off);
  if (lane == 0) c[gw] = s;
}

// d[g] = bz[g] + dot(Wz[g,:], c)   (one BLOCK per g, 256 threads)
__global__ __launch_bounds__(256) void dvec_k(const float* __restrict__ Wz,
                                              const float* __restrict__ bz,
                                              const float* __restrict__ c,
                                              float* __restrict__ d) {
  __shared__ float sb[4];
  int g = blockIdx.x, tid = threadIdx.x;
  const float* row = Wz + (size_t)g * (NH * EMB);
  float s = 0.f;
#pragma unroll
  for (int p = 0; p < 8; ++p) {
    int i = p * 256 + tid;
    float4 w = ((const float4*)row)[i];
    float4 cv = ((const float4*)c)[i];
    s += w.x * cv.x + w.y * cv.y + w.z * cv.z + w.w * cv.w;
  }
  int lane = tid & 63, w = tid >> 6;
#pragma unroll
  for (int off = 32; off; off >>= 1) s += __shfl_down(s, off);
  if (lane == 0) sb[w] = s;
  __syncthreads();
  if (tid == 0) d[g] = bz[g] + sb[0] + sb[1] + sb[2] + sb[3];
}

// MT[g][e] = bf16( sum_h Mp[h][e][g] )
__global__ __launch_bounds__(256) void mred_tr_k(const float* __restrict__ Mp,
                                                 unsigned short* __restrict__ MT) {
  __shared__ float t[32][33];
  int g0 = blockIdx.x * 32, e0 = blockIdx.y * 32;
  int tx = threadIdx.x & 31, ty = threadIdx.x >> 5;
#pragma unroll
  for (int k = 0; k < 4; ++k) {
    int e = e0 + ty + k * 8;
    float s = 0.f;
#pragma unroll
    for (int h = 0; h < NH; ++h)
      s += Mp[((size_t)h << 20) + (size_t)e * EMB + g0 + tx];
    t[ty + k * 8][tx] = s;
  }
  __syncthreads();
#pragma unroll
  for (int k = 0; k < 4; ++k) {
    int r = ty + k * 8;
    MT[(size_t)(g0 + r) * EMB + e0 + tx] = f2bf(t[tx][r]);
  }
}

// Gbf[i] = bf16( sum_z Gp[z][i] ), float4-granular
__global__ __launch_bounds__(256) void gram_red_k(const float* __restrict__ Gp,
                                                  unsigned short* __restrict__ Gbf) {
  int i = blockIdx.x * 256 + threadIdx.x;  // grid = EMB*EMB/4/256
  float4 s = ((const float4*)Gp)[i];
#pragma unroll
  for (int z = 1; z < 8; ++z) {
    float4 v = ((const float4*)(Gp + (size_t)z * EMB * EMB))[i];
    s.x += v.x; s.y += v.y; s.z += v.z; s.w += v.w;
  }
  ushort4 o; o.x = f2bf(s.x); o.y = f2bf(s.y); o.z = f2bf(s.z); o.w = f2bf(s.w);
  ((ushort4*)Gbf)[i] = o;
}

// ---------------------------------------------------------------- softmax / LN
__global__ __launch_bounds__(256) void softmax_k(const float* __restrict__ Sc,
                                                 unsigned short* __restrict__ A) {
  __shared__ float sb[8];
  int row = blockIdx.x, h = blockIdx.y, tid = threadIdx.x;
  const float* x = Sc + ((size_t)h * EMB + row) * EMB;
  unsigned short* out = A + ((size_t)h * EMB + row) * EMB;
  float4 v = ((const float4*)x)[tid];
  float mx = fmaxf(fmaxf(v.x, v.y), fmaxf(v.z, v.w));
  int lane = tid & 63, w = tid >> 6;
#pragma unroll
  for (int off = 32; off; off >>= 1) mx = fmaxf(mx, __shfl_down(mx, off));
  if (lane == 0) sb[w] = mx;
  __syncthreads();
  mx = fmaxf(fmaxf(sb[0], sb[1]), fmaxf(sb[2], sb[3]));
  float e0 = __expf(v.x - mx), e1 = __expf(v.y - mx);
  float e2 = __expf(v.z - mx), e3 = __expf(v.w - mx);
  float sm = e0 + e1 + e2 + e3;
#pragma unroll
  for (int off = 32; off; off >>= 1) sm += __shfl_down(sm, off);
  __syncthreads();
  if (lane == 0) sb[4 + w] = sm;
  __syncthreads();
  float inv = 1.0f / (sb[4] + sb[5] + sb[6] + sb[7]);
  ushort4 o;
  o.x = f2bf(e0 * inv); o.y = f2bf(e1 * inv); o.z = f2bf(e2 * inv); o.w = f2bf(e3 * inv);
  ((ushort4*)out)[tid] = o;
}

__global__ __launch_bounds__(256) void layernorm_k(const float* __restrict__ Xin,
                                                   const float* __restrict__ resid,
                                                   const float* __restrict__ gw,
                                                   const float* __restrict__ bw,
                                                   float* __restrict__ outf,
                                                   unsigned short* __restrict__ outb) {
  __shared__ float sb[16];
  int row = blockIdx.x, tid = threadIdx.x;
  float4 v = ((const float4*)(Xin + (size_t)row * EMB))[tid];
  float s = v.x + v.y + v.z + v.w;
  float q = v.x * v.x + v.y * v.y + v.z * v.z + v.w * v.w;
  int lane = tid & 63, w = tid >> 6;
#pragma unroll
  for (int off = 32; off; off >>= 1) { s += __shfl_down(s, off); q += __shfl_down(q, off); }
  if (lane == 0) { sb[w] = s; sb[8 + w] = q; }
  __syncthreads();
  float mu  = (sb[0] + sb[1] + sb[2] + sb[3]) * (1.0f / EMB);
  float var = (sb[8] + sb[9] + sb[10] + sb[11]) * (1.0f / EMB) - mu * mu;
  float rs = rsqrtf(var + 1e-5f);
  float4 rv = ((const float4*)(resid + (size_t)row * EMB))[tid];
  float4 gv = ((const float4*)gw)[tid];
  float4 bv = ((const float4*)bw)[tid];
  float o0 = (v.x - mu) * rs * gv.x + bv.x + rv.x;
  float o1 = (v.y - mu) * rs * gv.y + bv.y + rv.y;
  float o2 = (v.z - mu) * rs * gv.z + bv.z + rv.z;
  float o3 = (v.w - mu) * rs * gv.w + bv.w + rv.w;
  float4 ov; ov.x = o0; ov.y = o1; ov.z = o2; ov.w = o3;
  ((float4*)(outf + (size_t)row * EMB))[tid] = ov;
  if (outb) {
    ushort4 ob; ob.x = f2bf(o0); ob.y = f2bf(o1); ob.z = f2bf(o2); ob.w = f2bf(o3);
    ((ushort4*)(outb + (size_t)row * EMB))[tid] = ob;
  }
}

// ---------------------------------------------------------------- GEMM (NT)
// C[m,n] = sum_k A[m*lda+k] * B[n*ldb+k], bf16 in, f32 acc.
// MODE 0: f32 store. 1: bf16 store. 2: scores epilogue. 3: +bias[n], f32.
// 128x128 tile, BK=64, 4 waves, 16x16x32 MFMA, global_load_lds staging.
template <int MODE>
__global__ __launch_bounds__(256) void gemm_nt(const unsigned short* __restrict__ A,
                                               const unsigned short* __restrict__ B,
                                               void* __restrict__ Cout,
                                               int K, int lda, int ldb, int ldc,
                                               long long aZ, long long bZ, long long cZ,
                                               const float* __restrict__ e0,
                                               const float* __restrict__ e1,
                                               const float* __restrict__ e2,
                                               const float* __restrict__ e3) {
  const int z = blockIdx.z;
  A += (size_t)z * aZ;
  B += (size_t)z * bZ;
  const int tid = threadIdx.x;
  const int lane = tid & 63, wid = tid >> 6;
  const int wm = wid >> 1, wn = wid & 1;
  const int row0 = blockIdx.x * 128, col0 = blockIdx.y * 128;

  __shared__ __align__(16) unsigned short As[128 * 64];
  __shared__ __align__(16) unsigned short Bs[128 * 64];

  f32x4 acc[4][4] = {};
  const int lrow = lane & 15, kg = lane >> 4;
  const int lr = lane >> 3;        // row within an 8-row chunk
  const int lc = (lane & 7) * 8;   // elem col within 64

  for (int k0 = 0; k0 < K; k0 += 64) {
    // stage As/Bs [128][64] via direct global->LDS (1 KiB per instruction).
#pragma unroll
    for (int c = 0; c < 4; ++c) {
      int chunk = wid * 4 + c;           // 0..15, 8 rows each
      int r = chunk * 8 + lr;
      GLOAD_LDS16(A + (size_t)(row0 + r) * lda + k0 + lc, &As[chunk * 512]);
      GLOAD_LDS16(B + (size_t)(col0 + r) * ldb + k0 + lc, &Bs[chunk * 512]);
    }
    __syncthreads();
#pragma unroll
    for (int ks = 0; ks < 2; ++ks) {
      bf16x8 a[4], b[4];
      int koff = ks * 32 + kg * 8;
#pragma unroll
      for (int i = 0; i < 4; ++i)
        a[i] = *(const bf16x8*)&As[(wm * 64 + i * 16 + lrow) * 64 + koff];
#pragma unroll
      for (int j = 0; j < 4; ++j)
        b[j] = *(const bf16x8*)&Bs[(wn * 64 + j * 16 + lrow) * 64 + koff];
#pragma unroll
      for (int i = 0; i < 4; ++i)
#pragma unroll
        for (int j = 0; j < 4; ++j)
          acc[i][j] = __builtin_amdgcn_mfma_f32_16x16x32_bf16(a[i], b[j], acc[i][j], 0, 0, 0);
    }
    __syncthreads();
  }

  const int rb = (lane >> 4) * 4, cc = lane & 15;
#pragma unroll
  for (int i = 0; i < 4; ++i) {
#pragma unroll
    for (int j = 0; j < 4; ++j) {
#pragma unroll
      for (int r = 0; r < 4; ++r) {
        int m = row0 + wm * 64 + i * 16 + rb + r;
        int n = col0 + wn * 64 + j * 16 + cc;
        float val = acc[i][j][r];
        size_t off = (size_t)z * cZ + (size_t)m * ldc + n;
        if (MODE == 0) {
          ((float*)Cout)[off] = val;
        } else if (MODE == 1) {
          ((unsigned short*)Cout)[off] = f2bf(val);
        } else if (MODE == 2) {
          float uu = e0[z * EMB + m], bk = e1[z * EMB + m];
          float bq = e2[z * EMB + n], vv = e3[z * EMB + n];
          ((float*)Cout)[off] = (val + (uu + (float)SEQ * bk) * bq + bk * vv) * (1.0f / 32.0f);
        } else {
          ((float*)Cout)[off] = val + e0[n];
        }
      }
    }
  }
}

// ---------------------------------------------------------------- launch
extern "C" void kernel_launch(void* const* d_in, const int* in_sizes, int n_in,
                              void* d_out, int out_size, void* d_ws, size_t ws_size,
                              hipStream_t stream) {
  const float* history = (const float*)d_in[0];
  const float* emb     = (const float*)d_in[1];
  const float* Wq_w = (const float*)d_in[2];
  const float* Wq_b = (const float*)d_in[3];
  const float* Wk_w = (const float*)d_in[4];
  const float* Wk_b = (const float*)d_in[5];
  const float* Wv_w = (const float*)d_in[6];
  const float* Wv_b = (const float*)d_in[7];
  const float* Wz_w = (const float*)d_in[8];
  const float* Wz_b = (const float*)d_in[9];
  const float* ln1_g = (const float*)d_in[10];
  const float* ln1_b = (const float*)d_in[11];
  const float* Wf_w = (const float*)d_in[12];
  const float* Wf_b = (const float*)d_in[13];
  const float* ln2_g = (const float*)d_in[14];
  const float* ln2_b = (const float*)d_in[15];

  char* ws = (char*)d_ws;
  const size_t MB = 1024ull * 1024ull;
  unsigned short* XT  = (unsigned short*)(ws + 0);        // [E][S] bf16, 8MB ; later LN1bf
  unsigned short* Ybf = (unsigned short*)(ws + 8 * MB);   // [S][E] bf16, 8MB
  unsigned short* Wkb = (unsigned short*)(ws + 16 * MB);  // [H][E][E] bf16, 16MB
  unsigned short* Wqb = (unsigned short*)(ws + 32 * MB);
  unsigned short* WvT = (unsigned short*)(ws + 48 * MB);  // [H][E][E'] transposed
  unsigned short* Wzb = (unsigned short*)(ws + 64 * MB);  // [E][H*E]
  unsigned short* Wfb = (unsigned short*)(ws + 80 * MB);  // [E][E], 2MB
  unsigned short* Gbf = (unsigned short*)(ws + 82 * MB);  // [E][E] bf16 (symmetric), 2MB
  float* xpart = (float*)(ws + 84 * MB);                  // 32*1024 f32
  float* xbar  = (float*)(ws + 84 * MB + 256 * 1024);
  float* ubuf  = (float*)(ws + 84 * MB + 320 * 1024);     // [H][E]
  float* vbuf  = (float*)(ws + 84 * MB + 384 * 1024);
  float* cbuf  = (float*)(ws + 84 * MB + 448 * 1024);     // [H][E]
  float* dbuf  = (float*)(ws + 84 * MB + 512 * 1024);     // [E]
  unsigned short* Tbf = (unsigned short*)(ws + 85 * MB);  // 16MB; later Cbf, later FN f32
  float* Sc  = (float*)(ws + 101 * MB);                   // 32MB: Gram partials, scores, Mp
  unsigned short* Abf = (unsigned short*)(ws + 133 * MB); // 16MB; later O f32
  unsigned short* ATb = (unsigned short*)(ws + 149 * MB); // 16MB; later LN1 f32
  unsigned short* MTb = (unsigned short*)(ws + 165 * MB); // 2MB
  // aliases (lifetimes verified non-overlapping)
  float* Gp   = Sc;     // [8][E][E] split-K Gram partials (before scores)
  unsigned short* Cbf  = Tbf;
  float* Mp   = Sc;
  float* Obuf = (float*)Abf;
  float* LN1  = (float*)ATb;
  unsigned short* LN1b = XT;
  float* FN   = (float*)Tbf;

  auto cgrid = [](int n4) { return dim3((n4 + 255) / 256); };

  // --- xbar first (needed by fused conversion+dot)
  colsum_part_k<<<dim3(4, 32), 256, 0, stream>>>(emb, xpart);
  colsum_red_k<<<dim3(4), 256, 0, stream>>>(xpart, xbar);

  // --- input conversions (f32 -> bf16); Wk/Wq fused with xbar dot (u, v)
  cvt_bf16_k<<<cgrid(SEQ * EMB / 4), 256, 0, stream>>>(history, Ybf, SEQ * EMB / 4);
  cvt_dot_k<<<dim3(NH * EMB), 256, 0, stream>>>(Wk_w, Wkb, xbar, ubuf);
  cvt_dot_k<<<dim3(NH * EMB), 256, 0, stream>>>(Wq_w, Wqb, xbar, vbuf);
  cvt_bf16_k<<<cgrid(NH * EMB * EMB / 4), 256, 0, stream>>>(Wz_w, Wzb, NH * EMB * EMB / 4);
  cvt_bf16_k<<<cgrid(EMB * EMB / 4), 256, 0, stream>>>(Wf_w, Wfb, EMB * EMB / 4);
  tr_f32_bf16_k<<<dim3(EMB / 32, SEQ / 32, 1), 256, 0, stream>>>(emb, XT, SEQ, EMB);
  tr_f32_bf16_k<<<dim3(EMB / 32, EMB / 32, NH), 256, 0, stream>>>(Wv_w, WvT, EMB, EMB);

  // --- G = XT * XT^T, split-K over z (8 x K=512) -> f32 partials -> bf16
  gemm_nt<0><<<dim3(8, 8, 8), 256, 0, stream>>>(XT, XT, Gp, 512, SEQ, SEQ, EMB,
                                                512, 512, (long long)EMB * EMB,
                                                nullptr, nullptr, nullptr, nullptr);
  gram_red_k<<<cgrid(EMB * EMB / 4), 256, 0, stream>>>(Gp, Gbf);
  // --- T_h = Wk_h * G   (uses G symmetry for the NT B-operand)
  gemm_nt<1><<<dim3(8, 8, NH), 256, 0, stream>>>(Wkb, Gbf, Tbf, EMB, EMB, EMB, EMB,
                                                 (long long)EMB * EMB, 0, (long long)EMB * EMB,
                                                 nullptr, nullptr, nullptr, nullptr);
  // --- scores_h = T_h * Wq_h^T / 32 + rank-1 bias terms
  gemm_nt<2><<<dim3(8, 8, NH), 256, 0, stream>>>(Tbf, Wqb, Sc, EMB, EMB, EMB, EMB,
                                                 (long long)EMB * EMB, (long long)EMB * EMB,
                                                 (long long)EMB * EMB, ubuf, Wk_b, Wq_b, vbuf);
  // --- A = softmax rows, AT = A^T
  softmax_k<<<dim3(EMB, NH), 256, 0, stream>>>(Sc, Abf);
  tr_bf16_k<<<dim3(EMB / 32, EMB / 32, NH), 256, 0, stream>>>(Abf, ATb, EMB, EMB);
  cvec_k<<<dim3(NH * EMB / 4), 256, 0, stream>>>(ATb, Wv_b, cbuf);
  // --- C_h = WvT_h * AT_h^T  == Wv_h^T A_h
  gemm_nt<1><<<dim3(8, 8, NH), 256, 0, stream>>>(WvT, ATb, Cbf, EMB, EMB, EMB, EMB,
                                                 (long long)EMB * EMB, (long long)EMB * EMB,
                                                 (long long)EMB * EMB,
                                                 nullptr, nullptr, nullptr, nullptr);
  // --- Mp_h = C_h * Wz_h^T  (f32)
  gemm_nt<0><<<dim3(8, 8, NH), 256, 0, stream>>>(Cbf, Wzb, Mp, EMB, EMB, NH * EMB, EMB,
                                                 (long long)EMB * EMB, (long long)EMB,
                                                 (long long)EMB * EMB,
                                                 nullptr, nullptr, nullptr, nullptr);
  // --- M = sum_h Mp_h, transposed+bf16 ; d vector
  mred_tr_k<<<dim3(EMB / 32, EMB / 32), 256, 0, stream>>>(Mp, MTb);
  dvec_k<<<dim3(EMB), 256, 0, stream>>>(Wz_w, Wz_b, cbuf, dbuf);
  // --- O = Y * M + d
  gemm_nt<3><<<dim3(SEQ / 128, 8, 1), 256, 0, stream>>>(Ybf, MTb, Obuf, EMB, EMB, EMB, EMB,
                                                        0, 0, 0, dbuf, nullptr, nullptr, nullptr);
  // --- LN1 = LN(O)+emb (f32 + bf16 copies)
  layernorm_k<<<dim3(SEQ), 256, 0, stream>>>(Obuf, emb, ln1_g, ln1_b, LN1, LN1b);
  // --- FN = LN1 * Wf^T + bf
  gemm_nt<3><<<dim3(SEQ / 128, 8, 1), 256, 0, stream>>>(LN1b, Wfb, FN, EMB, EMB, EMB, EMB,
                                                        0, 0, 0, Wf_b, nullptr, nullptr, nullptr);
  // --- out = LN(FN)+LN1
  layernorm_k<<<dim3(SEQ), 256, 0, stream>>>(FN, LN1, ln2_g, ln2_b, (float*)d_out, nullptr);
}

// Round 4
// 332.580 us; speedup vs baseline: 1.4187x; 1.0087x over previous
//
#include <hip/hip_runtime.h>

// AutoDecoderLayer on MI355X.
// Algebra: with X=embdding, Y=history,
//   G = X^T X  (E x E Gram, shared over heads)
//   scores_h = (Wk_h G Wq_h^T + u_h bq_h^T + bk_h v_h^T + S bk_h bq_h^T)/32
//   A_h = softmax_rows(scores_h)
//   M = sum_h Wv_h^T A_h Wz_h^T ;  d = bz + sum_h (bv_h^T A_h) Wz_h^T
//   O = Y M + d ; LN1 = LN(O)+X ; FN = LN1 Wf^T + bf ; out = LN(FN)+LN1
// ~95 GFLOP total. R1: global_load_lds + split-K Gram. R2: dvec parallelism,
// uv fused into conversions. R3: 2-phase double-buffered GEMM staging
// (stage k+1 issued before compute of k; one barrier per K-step).

constexpr int EMB = 1024;
constexpr int SEQ = 4096;
constexpr int NH  = 8;

using f32x4  = __attribute__((ext_vector_type(4))) float;
using bf16x8 = __attribute__((ext_vector_type(8))) __bf16;
using us8    = __attribute__((ext_vector_type(8))) unsigned short;

#define GLOAD_LDS16(g, l) __builtin_amdgcn_global_load_lds(                 \
    (const __attribute__((address_space(1))) void*)(g),                     \
    (__attribute__((address_space(3))) void*)(l), 16, 0, 0)

__device__ inline unsigned short f2bf(float x) {
  unsigned int u = __float_as_uint(x);
  u += 0x7FFFu + ((u >> 16) & 1u);   // round-to-nearest-even
  return (unsigned short)(u >> 16);
}
__device__ inline float bf2f(unsigned short h) {
  return __uint_as_float(((unsigned int)h) << 16);
}

// ---------------------------------------------------------------- conversions
__global__ __launch_bounds__(256) void cvt_bf16_k(const float* __restrict__ src,
                                                  unsigned short* __restrict__ dst,
                                                  int n4) {
  int i = blockIdx.x * 256 + threadIdx.x;
  if (i >= n4) return;
  float4 v = ((const float4*)src)[i];
  ushort4 o; o.x = f2bf(v.x); o.y = f2bf(v.y); o.z = f2bf(v.z); o.w = f2bf(v.w);
  ((ushort4*)dst)[i] = o;
}

// convert one 1024-elem row to bf16 AND dot it with xbar (one block per row)
__global__ __launch_bounds__(256) void cvt_dot_k(const float* __restrict__ src,
                                                 unsigned short* __restrict__ dst,
                                                 const float* __restrict__ xbar,
                                                 float* __restrict__ dotout) {
  __shared__ float sb[4];
  int row = blockIdx.x, tid = threadIdx.x;
  float4 v  = ((const float4*)(src + (size_t)row * EMB))[tid];
  float4 xb = ((const float4*)xbar)[tid];
  ushort4 o; o.x = f2bf(v.x); o.y = f2bf(v.y); o.z = f2bf(v.z); o.w = f2bf(v.w);
  ((ushort4*)(dst + (size_t)row * EMB))[tid] = o;
  float s = v.x * xb.x + v.y * xb.y + v.z * xb.z + v.w * xb.w;
  int lane = tid & 63, w = tid >> 6;
#pragma unroll
  for (int off = 32; off; off >>= 1) s += __shfl_down(s, off);
  if (lane == 0) sb[w] = s;
  __syncthreads();
  if (tid == 0) dotout[row] = sb[0] + sb[1] + sb[2] + sb[3];
}

// dst[z][c][r] = bf16(src[z][r][c]); grid (cols/32, rows/32, z), block 256
__global__ __launch_bounds__(256) void tr_f32_bf16_k(const float* __restrict__ src,
                                                     unsigned short* __restrict__ dst,
                                                     int rows, int cols) {
  __shared__ float t[32][33];
  size_t zoff = (size_t)blockIdx.z * rows * cols;
  int c0 = blockIdx.x * 32, r0 = blockIdx.y * 32;
  int tx = threadIdx.x & 31, ty = threadIdx.x >> 5;
#pragma unroll
  for (int k = 0; k < 4; ++k) {
    int r = ty + k * 8;
    t[r][tx] = src[zoff + (size_t)(r0 + r) * cols + c0 + tx];
  }
  __syncthreads();
#pragma unroll
  for (int k = 0; k < 4; ++k) {
    int r = ty + k * 8;
    dst[zoff + (size_t)(c0 + r) * rows + r0 + tx] = f2bf(t[tx][r]);
  }
}

// dst[z][c][r] = src[z][r][c], bf16
__global__ __launch_bounds__(256) void tr_bf16_k(const unsigned short* __restrict__ src,
                                                 unsigned short* __restrict__ dst,
                                                 int rows, int cols) {
  __shared__ unsigned short t[32][33];
  size_t zoff = (size_t)blockIdx.z * rows * cols;
  int c0 = blockIdx.x * 32, r0 = blockIdx.y * 32;
  int tx = threadIdx.x & 31, ty = threadIdx.x >> 5;
#pragma unroll
  for (int k = 0; k < 4; ++k) {
    int r = ty + k * 8;
    t[r][tx] = src[zoff + (size_t)(r0 + r) * cols + c0 + tx];
  }
  __syncthreads();
#pragma unroll
  for (int k = 0; k < 4; ++k) {
    int r = ty + k * 8;
    dst[zoff + (size_t)(c0 + r) * rows + r0 + tx] = t[tx][r];
  }
}

// ---------------------------------------------------------------- small vecs
__global__ __launch_bounds__(256) void colsum_part_k(const float* __restrict__ X,
                                                     float* __restrict__ part) {
  int e = blockIdx.x * 256 + threadIdx.x;  // grid.x = 4
  int y = blockIdx.y;                      // 32 chunks of 128 rows
  float s = 0.f;
  for (int r = y * 128; r < y * 128 + 128; ++r) s += X[(size_t)r * EMB + e];
  part[y * EMB + e] = s;
}
__global__ __launch_bounds__(256) void colsum_red_k(const float* __restrict__ part,
                                                    float* __restrict__ xbar) {
  int e = blockIdx.x * 256 + threadIdx.x;
  float s = 0.f;
  for (int y = 0; y < 32; ++y) s += part[y * EMB + e];
  xbar[e] = s;
}

// c[h,f] = sum_{e'} AT[h,f,e'] * bv[h,e']   (one wave per (h,f))
__global__ __launch_bounds__(256) void cvec_k(const unsigned short* __restrict__ AT,
                                              const float* __restrict__ bv,
                                              float* __restrict__ c) {
  int gw = blockIdx.x * 4 + (threadIdx.x >> 6);  // 0..NH*EMB-1
  int lane = threadIdx.x & 63;
  int h = gw >> 10;
  const unsigned short* row = AT + (size_t)gw * EMB;
  const float* bvh = bv + h * EMB;
  float s = 0.f;
  for (int k = lane; k < EMB; k += 64) s += bf2f(row[k]) * bvh[k];
#pragma unroll
  for (int off = 32; off; off >>= 1) s += __shfl_down(s, off);
  if (lane == 0) c[gw] = s;
}

// d[g] = bz[g] + dot(Wz[g,:], c)   (one BLOCK per g, 256 threads)
__global__ __launch_bounds__(256) void dvec_k(const float* __restrict__ Wz,
                                              const float* __restrict__ bz,
                                              const float* __restrict__ c,
                                              float* __restrict__ d) {
  __shared__ float sb[4];
  int g = blockIdx.x, tid = threadIdx.x;
  const float* row = Wz + (size_t)g * (NH * EMB);
  float s = 0.f;
#pragma unroll
  for (int p = 0; p < 8; ++p) {
    int i = p * 256 + tid;
    float4 w = ((const float4*)row)[i];
    float4 cv = ((const float4*)c)[i];
    s += w.x * cv.x + w.y * cv.y + w.z * cv.z + w.w * cv.w;
  }
  int lane = tid & 63, w = tid >> 6;
#pragma unroll
  for (int off = 32; off; off >>= 1) s += __shfl_down(s, off);
  if (lane == 0) sb[w] = s;
  __syncthreads();
  if (tid == 0) d[g] = bz[g] + sb[0] + sb[1] + sb[2] + sb[3];
}

// MT[g][e] = bf16( sum_h Mp[h][e][g] )
__global__ __launch_bounds__(256) void mred_tr_k(const float* __restrict__ Mp,
                                                 unsigned short* __restrict__ MT) {
  __shared__ float t[32][33];
  int g0 = blockIdx.x * 32, e0 = blockIdx.y * 32;
  int tx = threadIdx.x & 31, ty = threadIdx.x >> 5;
#pragma unroll
  for (int k = 0; k < 4; ++k) {
    int e = e0 + ty + k * 8;
    float s = 0.f;
#pragma unroll
    for (int h = 0; h < NH; ++h)
      s += Mp[((size_t)h << 20) + (size_t)e * EMB + g0 + tx];
    t[ty + k * 8][tx] = s;
  }
  __syncthreads();
#pragma unroll
  for (int k = 0; k < 4; ++k) {
    int r = ty + k * 8;
    MT[(size_t)(g0 + r) * EMB + e0 + tx] = f2bf(t[tx][r]);
  }
}

// Gbf[i] = bf16( sum_z Gp[z][i] ), float4-granular
__global__ __launch_bounds__(256) void gram_red_k(const float* __restrict__ Gp,
                                                  unsigned short* __restrict__ Gbf) {
  int i = blockIdx.x * 256 + threadIdx.x;  // grid = EMB*EMB/4/256
  float4 s = ((const float4*)Gp)[i];
#pragma unroll
  for (int z = 1; z < 8; ++z) {
    float4 v = ((const float4*)(Gp + (size_t)z * EMB * EMB))[i];
    s.x += v.x; s.y += v.y; s.z += v.z; s.w += v.w;
  }
  ushort4 o; o.x = f2bf(s.x); o.y = f2bf(s.y); o.z = f2bf(s.z); o.w = f2bf(s.w);
  ((ushort4*)Gbf)[i] = o;
}

// ---------------------------------------------------------------- softmax / LN
__global__ __launch_bounds__(256) void softmax_k(const float* __restrict__ Sc,
                                                 unsigned short* __restrict__ A) {
  __shared__ float sb[8];
  int row = blockIdx.x, h = blockIdx.y, tid = threadIdx.x;
  const float* x = Sc + ((size_t)h * EMB + row) * EMB;
  unsigned short* out = A + ((size_t)h * EMB + row) * EMB;
  float4 v = ((const float4*)x)[tid];
  float mx = fmaxf(fmaxf(v.x, v.y), fmaxf(v.z, v.w));
  int lane = tid & 63, w = tid >> 6;
#pragma unroll
  for (int off = 32; off; off >>= 1) mx = fmaxf(mx, __shfl_down(mx, off));
  if (lane == 0) sb[w] = mx;
  __syncthreads();
  mx = fmaxf(fmaxf(sb[0], sb[1]), fmaxf(sb[2], sb[3]));
  float e0 = __expf(v.x - mx), e1 = __expf(v.y - mx);
  float e2 = __expf(v.z - mx), e3 = __expf(v.w - mx);
  float sm = e0 + e1 + e2 + e3;
#pragma unroll
  for (int off = 32; off; off >>= 1) sm += __shfl_down(sm, off);
  __syncthreads();
  if (lane == 0) sb[4 + w] = sm;
  __syncthreads();
  float inv = 1.0f / (sb[4] + sb[5] + sb[6] + sb[7]);
  ushort4 o;
  o.x = f2bf(e0 * inv); o.y = f2bf(e1 * inv); o.z = f2bf(e2 * inv); o.w = f2bf(e3 * inv);
  ((ushort4*)out)[tid] = o;
}

__global__ __launch_bounds__(256) void layernorm_k(const float* __restrict__ Xin,
                                                   const float* __restrict__ resid,
                                                   const float* __restrict__ gw,
                                                   const float* __restrict__ bw,
                                                   float* __restrict__ outf,
                                                   unsigned short* __restrict__ outb) {
  __shared__ float sb[16];
  int row = blockIdx.x, tid = threadIdx.x;
  float4 v = ((const float4*)(Xin + (size_t)row * EMB))[tid];
  float s = v.x + v.y + v.z + v.w;
  float q = v.x * v.x + v.y * v.y + v.z * v.z + v.w * v.w;
  int lane = tid & 63, w = tid >> 6;
#pragma unroll
  for (int off = 32; off; off >>= 1) { s += __shfl_down(s, off); q += __shfl_down(q, off); }
  if (lane == 0) { sb[w] = s; sb[8 + w] = q; }
  __syncthreads();
  float mu  = (sb[0] + sb[1] + sb[2] + sb[3]) * (1.0f / EMB);
  float var = (sb[8] + sb[9] + sb[10] + sb[11]) * (1.0f / EMB) - mu * mu;
  float rs = rsqrtf(var + 1e-5f);
  float4 rv = ((const float4*)(resid + (size_t)row * EMB))[tid];
  float4 gv = ((const float4*)gw)[tid];
  float4 bv = ((const float4*)bw)[tid];
  float o0 = (v.x - mu) * rs * gv.x + bv.x + rv.x;
  float o1 = (v.y - mu) * rs * gv.y + bv.y + rv.y;
  float o2 = (v.z - mu) * rs * gv.z + bv.z + rv.z;
  float o3 = (v.w - mu) * rs * gv.w + bv.w + rv.w;
  float4 ov; ov.x = o0; ov.y = o1; ov.z = o2; ov.w = o3;
  ((float4*)(outf + (size_t)row * EMB))[tid] = ov;
  if (outb) {
    ushort4 ob; ob.x = f2bf(o0); ob.y = f2bf(o1); ob.z = f2bf(o2); ob.w = f2bf(o3);
    ((ushort4*)(outb + (size_t)row * EMB))[tid] = ob;
  }
}

// ---------------------------------------------------------------- GEMM (NT)
// C[m,n] = sum_k A[m*lda+k] * B[n*ldb+k], bf16 in, f32 acc.
// MODE 0: f32 store. 1: bf16 store. 2: scores epilogue. 3: +bias[n], f32.
// 128x128 tile, BK=64, 4 waves, 16x16x32 MFMA.
// 2-phase double-buffered global_load_lds staging: stage of tile t+1 is
// issued BEFORE the ds_read+MFMA of tile t; the single __syncthreads per
// iteration (compiler emits vmcnt(0)+lgkmcnt(0)+s_barrier) then drains a
// load that has had the whole MFMA phase to land. Barrier also guarantees
// all waves finished reading buf[t&1] before iter t+1 stages into it.
template <int MODE>
__global__ __launch_bounds__(256) void gemm_nt(const unsigned short* __restrict__ A,
                                               const unsigned short* __restrict__ B,
                                               void* __restrict__ Cout,
                                               int K, int lda, int ldb, int ldc,
                                               long long aZ, long long bZ, long long cZ,
                                               const float* __restrict__ e0,
                                               const float* __restrict__ e1,
                                               const float* __restrict__ e2,
                                               const float* __restrict__ e3) {
  const int z = blockIdx.z;
  A += (size_t)z * aZ;
  B += (size_t)z * bZ;
  const int tid = threadIdx.x;
  const int lane = tid & 63, wid = tid >> 6;
  const int wm = wid >> 1, wn = wid & 1;
  const int row0 = blockIdx.x * 128, col0 = blockIdx.y * 128;

  __shared__ __align__(16) unsigned short As[2][128 * 64];
  __shared__ __align__(16) unsigned short Bs[2][128 * 64];

  f32x4 acc[4][4] = {};
  const int lrow = lane & 15, kg = lane >> 4;
  const int lr = lane >> 3;        // row within an 8-row chunk
  const int lc = (lane & 7) * 8;   // elem col within 64

  // stage [128][64] A/B tiles at k0 into buffer buf (async, 1 KiB/instr)
  auto stage = [&](int buf, int k0) {
#pragma unroll
    for (int c = 0; c < 4; ++c) {
      int chunk = wid * 4 + c;           // 0..15, 8 rows each
      int r = chunk * 8 + lr;
      GLOAD_LDS16(A + (size_t)(row0 + r) * lda + k0 + lc, &As[buf][chunk * 512]);
      GLOAD_LDS16(B + (size_t)(col0 + r) * ldb + k0 + lc, &Bs[buf][chunk * 512]);
    }
  };

  stage(0, 0);
  __syncthreads();

  const int nt = K >> 6;
  for (int t = 0; t < nt; ++t) {
    const int cur = t & 1;
    if (t + 1 < nt) stage(cur ^ 1, (t + 1) << 6);
#pragma unroll
    for (int ks = 0; ks < 2; ++ks) {
      bf16x8 a[4], b[4];
      int koff = ks * 32 + kg * 8;
#pragma unroll
      for (int i = 0; i < 4; ++i)
        a[i] = *(const bf16x8*)&As[cur][(wm * 64 + i * 16 + lrow) * 64 + koff];
#pragma unroll
      for (int j = 0; j < 4; ++j)
        b[j] = *(const bf16x8*)&Bs[cur][(wn * 64 + j * 16 + lrow) * 64 + koff];
#pragma unroll
      for (int i = 0; i < 4; ++i)
#pragma unroll
        for (int j = 0; j < 4; ++j)
          acc[i][j] = __builtin_amdgcn_mfma_f32_16x16x32_bf16(a[i], b[j], acc[i][j], 0, 0, 0);
    }
    __syncthreads();
  }

  const int rb = (lane >> 4) * 4, cc = lane & 15;
#pragma unroll
  for (int i = 0; i < 4; ++i) {
#pragma unroll
    for (int j = 0; j < 4; ++j) {
#pragma unroll
      for (int r = 0; r < 4; ++r) {
        int m = row0 + wm * 64 + i * 16 + rb + r;
        int n = col0 + wn * 64 + j * 16 + cc;
        float val = acc[i][j][r];
        size_t off = (size_t)z * cZ + (size_t)m * ldc + n;
        if (MODE == 0) {
          ((float*)Cout)[off] = val;
        } else if (MODE == 1) {
          ((unsigned short*)Cout)[off] = f2bf(val);
        } else if (MODE == 2) {
          float uu = e0[z * EMB + m], bk = e1[z * EMB + m];
          float bq = e2[z * EMB + n], vv = e3[z * EMB + n];
          ((float*)Cout)[off] = (val + (uu + (float)SEQ * bk) * bq + bk * vv) * (1.0f / 32.0f);
        } else {
          ((float*)Cout)[off] = val + e0[n];
        }
      }
    }
  }
}

// ---------------------------------------------------------------- launch
extern "C" void kernel_launch(void* const* d_in, const int* in_sizes, int n_in,
                              void* d_out, int out_size, void* d_ws, size_t ws_size,
                              hipStream_t stream) {
  const float* history = (const float*)d_in[0];
  const float* emb     = (const float*)d_in[1];
  const float* Wq_w = (const float*)d_in[2];
  const float* Wq_b = (const float*)d_in[3];
  const float* Wk_w = (const float*)d_in[4];
  const float* Wk_b = (const float*)d_in[5];
  const float* Wv_w = (const float*)d_in[6];
  const float* Wv_b = (const float*)d_in[7];
  const float* Wz_w = (const float*)d_in[8];
  const float* Wz_b = (const float*)d_in[9];
  const float* ln1_g = (const float*)d_in[10];
  const float* ln1_b = (const float*)d_in[11];
  const float* Wf_w = (const float*)d_in[12];
  const float* Wf_b = (const float*)d_in[13];
  const float* ln2_g = (const float*)d_in[14];
  const float* ln2_b = (const float*)d_in[15];

  char* ws = (char*)d_ws;
  const size_t MB = 1024ull * 1024ull;
  unsigned short* XT  = (unsigned short*)(ws + 0);        // [E][S] bf16, 8MB ; later LN1bf
  unsigned short* Ybf = (unsigned short*)(ws + 8 * MB);   // [S][E] bf16, 8MB
  unsigned short* Wkb = (unsigned short*)(ws + 16 * MB);  // [H][E][E] bf16, 16MB
  unsigned short* Wqb = (unsigned short*)(ws + 32 * MB);
  unsigned short* WvT = (unsigned short*)(ws + 48 * MB);  // [H][E][E'] transposed
  unsigned short* Wzb = (unsigned short*)(ws + 64 * MB);  // [E][H*E]
  unsigned short* Wfb = (unsigned short*)(ws + 80 * MB);  // [E][E], 2MB
  unsigned short* Gbf = (unsigned short*)(ws + 82 * MB);  // [E][E] bf16 (symmetric), 2MB
  float* xpart = (float*)(ws + 84 * MB);                  // 32*1024 f32
  float* xbar  = (float*)(ws + 84 * MB + 256 * 1024);
  float* ubuf  = (float*)(ws + 84 * MB + 320 * 1024);     // [H][E]
  float* vbuf  = (float*)(ws + 84 * MB + 384 * 1024);
  float* cbuf  = (float*)(ws + 84 * MB + 448 * 1024);     // [H][E]
  float* dbuf  = (float*)(ws + 84 * MB + 512 * 1024);     // [E]
  unsigned short* Tbf = (unsigned short*)(ws + 85 * MB);  // 16MB; later Cbf, later FN f32
  float* Sc  = (float*)(ws + 101 * MB);                   // 32MB: Gram partials, scores, Mp
  unsigned short* Abf = (unsigned short*)(ws + 133 * MB); // 16MB; later O f32
  unsigned short* ATb = (unsigned short*)(ws + 149 * MB); // 16MB; later LN1 f32
  unsigned short* MTb = (unsigned short*)(ws + 165 * MB); // 2MB
  // aliases (lifetimes verified non-overlapping)
  float* Gp   = Sc;     // [8][E][E] split-K Gram partials (before scores)
  unsigned short* Cbf  = Tbf;
  float* Mp   = Sc;
  float* Obuf = (float*)Abf;
  float* LN1  = (float*)ATb;
  unsigned short* LN1b = XT;
  float* FN   = (float*)Tbf;

  auto cgrid = [](int n4) { return dim3((n4 + 255) / 256); };

  // --- xbar first (needed by fused conversion+dot)
  colsum_part_k<<<dim3(4, 32), 256, 0, stream>>>(emb, xpart);
  colsum_red_k<<<dim3(4), 256, 0, stream>>>(xpart, xbar);

  // --- input conversions (f32 -> bf16); Wk/Wq fused with xbar dot (u, v)
  cvt_bf16_k<<<cgrid(SEQ * EMB / 4), 256, 0, stream>>>(history, Ybf, SEQ * EMB / 4);
  cvt_dot_k<<<dim3(NH * EMB), 256, 0, stream>>>(Wk_w, Wkb, xbar, ubuf);
  cvt_dot_k<<<dim3(NH * EMB), 256, 0, stream>>>(Wq_w, Wqb, xbar, vbuf);
  cvt_bf16_k<<<cgrid(NH * EMB * EMB / 4), 256, 0, stream>>>(Wz_w, Wzb, NH * EMB * EMB / 4);
  cvt_bf16_k<<<cgrid(EMB * EMB / 4), 256, 0, stream>>>(Wf_w, Wfb, EMB * EMB / 4);
  tr_f32_bf16_k<<<dim3(EMB / 32, SEQ / 32, 1), 256, 0, stream>>>(emb, XT, SEQ, EMB);
  tr_f32_bf16_k<<<dim3(EMB / 32, EMB / 32, NH), 256, 0, stream>>>(Wv_w, WvT, EMB, EMB);

  // --- G = XT * XT^T, split-K over z (8 x K=512) -> f32 partials -> bf16
  gemm_nt<0><<<dim3(8, 8, 8), 256, 0, stream>>>(XT, XT, Gp, 512, SEQ, SEQ, EMB,
                                                512, 512, (long long)EMB * EMB,
                                                nullptr, nullptr, nullptr, nullptr);
  gram_red_k<<<cgrid(EMB * EMB / 4), 256, 0, stream>>>(Gp, Gbf);
  // --- T_h = Wk_h * G   (uses G symmetry for the NT B-operand)
  gemm_nt<1><<<dim3(8, 8, NH), 256, 0, stream>>>(Wkb, Gbf, Tbf, EMB, EMB, EMB, EMB,
                                                 (long long)EMB * EMB, 0, (long long)EMB * EMB,
                                                 nullptr, nullptr, nullptr, nullptr);
  // --- scores_h = T_h * Wq_h^T / 32 + rank-1 bias terms
  gemm_nt<2><<<dim3(8, 8, NH), 256, 0, stream>>>(Tbf, Wqb, Sc, EMB, EMB, EMB, EMB,
                                                 (long long)EMB * EMB, (long long)EMB * EMB,
                                                 (long long)EMB * EMB, ubuf, Wk_b, Wq_b, vbuf);
  // --- A = softmax rows, AT = A^T
  softmax_k<<<dim3(EMB, NH), 256, 0, stream>>>(Sc, Abf);
  tr_bf16_k<<<dim3(EMB / 32, EMB / 32, NH), 256, 0, stream>>>(Abf, ATb, EMB, EMB);
  cvec_k<<<dim3(NH * EMB / 4), 256, 0, stream>>>(ATb, Wv_b, cbuf);
  // --- C_h = WvT_h * AT_h^T  == Wv_h^T A_h
  gemm_nt<1><<<dim3(8, 8, NH), 256, 0, stream>>>(WvT, ATb, Cbf, EMB, EMB, EMB, EMB,
                                                 (long long)EMB * EMB, (long long)EMB * EMB,
                                                 (long long)EMB * EMB,
                                                 nullptr, nullptr, nullptr, nullptr);
  // --- Mp_h = C_h * Wz_h^T  (f32)
  gemm_nt<0><<<dim3(8, 8, NH), 256, 0, stream>>>(Cbf, Wzb, Mp, EMB, EMB, NH * EMB, EMB,
                                                 (long long)EMB * EMB, (long long)EMB,
                                                 (long long)EMB * EMB,
                                                 nullptr, nullptr, nullptr, nullptr);
  // --- M = sum_h Mp_h, transposed+bf16 ; d vector
  mred_tr_k<<<dim3(EMB / 32, EMB / 32), 256, 0, stream>>>(Mp, MTb);
  dvec_k<<<dim3(EMB), 256, 0, stream>>>(Wz_w, Wz_b, cbuf, dbuf);
  // --- O = Y * M + d
  gemm_nt<3><<<dim3(SEQ / 128, 8, 1), 256, 0, stream>>>(Ybf, MTb, Obuf, EMB, EMB, EMB, EMB,
                                                        0, 0, 0, dbuf, nullptr, nullptr, nullptr);
  // --- LN1 = LN(O)+emb (f32 + bf16 copies)
  layernorm_k<<<dim3(SEQ), 256, 0, stream>>>(Obuf, emb, ln1_g, ln1_b, LN1, LN1b);
  // --- FN = LN1 * Wf^T + bf
  gemm_nt<3><<<dim3(SEQ / 128, 8, 1), 256, 0, stream>>>(LN1b, Wfb, FN, EMB, EMB, EMB, EMB,
                                                        0, 0, 0, Wf_b, nullptr, nullptr, nullptr);
  // --- out = LN(FN)+LN1
  layernorm_k<<<dim3(SEQ), 256, 0, stream>>>(FN, LN1, ln2_g, ln2_b, (float*)d_out, nullptr);
}

// Round 5
// 301.786 us; speedup vs baseline: 1.5634x; 1.1020x over previous
//
#include <hip/hip_runtime.h>

// AutoDecoderLayer on MI355X.
// Algebra: with X=embdding, Y=history,
//   G = X^T X  (E x E Gram, shared over heads)
//   scoresT_h = (Wq_h G Wk_h^T + bq_h u_h^T + v_h bk_h^T + S bq_h bk_h^T)/32
//       (= scores^T since G symmetric); softmax over scores' last axis
//       == per-COLUMN softmax of scoresT -> coalesced stats + direct AT.
//   AT_h = colsoftmax(scoresT_h) ; c_h = AT_h bv_h
//   M = sum_h Wv_h^T A_h Wz_h^T ;  d = bz + sum_h c_h^T ... (via Wz)
//   O = Y M + d ; LN1 = LN(O)+X ; FN = LN1 Wf^T + bf ; out = LN(FN)+LN1
// R1: global_load_lds + split-K Gram. R2: dvec/uv parallelism. R3: 2ph dbuf
// (neutral, kept). R4: mega-fused conversions, transposed-scores softmax
// (no separate transpose), bf16 partials for Gram/Mp, bf16 dvec.

constexpr int EMB = 1024;
constexpr int SEQ = 4096;
constexpr int NH  = 8;

using f32x4  = __attribute__((ext_vector_type(4))) float;
using bf16x8 = __attribute__((ext_vector_type(8))) __bf16;
using us8    = __attribute__((ext_vector_type(8))) unsigned short;

#define GLOAD_LDS16(g, l) __builtin_amdgcn_global_load_lds(                 \
    (const __attribute__((address_space(1))) void*)(g),                     \
    (__attribute__((address_space(3))) void*)(l), 16, 0, 0)

__device__ inline unsigned short f2bf(float x) {
  unsigned int u = __float_as_uint(x);
  u += 0x7FFFu + ((u >> 16) & 1u);   // round-to-nearest-even
  return (unsigned short)(u >> 16);
}
__device__ inline float bf2f(unsigned short h) {
  return __uint_as_float(((unsigned int)h) << 16);
}

// ------------------------------------------------ mega conversion kernel
// One dispatch for every prologue transform (after xbar is ready):
//  [0,8192)      : Wk row -> bf16 + dot(xbar) -> u
//  [8192,16384)  : Wq row -> bf16 + dot(xbar) -> v
//  [16384,20480) : history row -> bf16
//  [20480,28672) : Wz row -> bf16
//  [28672,29696) : Wf row -> bf16
//  [29696,33792) : emb 32x32 transpose tile -> XT bf16
//  [33792,41984) : Wv 32x32 transpose tile (per head) -> WvT bf16
__global__ __launch_bounds__(256) void mega_cvt_k(
    const float* __restrict__ Wk, const float* __restrict__ Wq,
    const float* __restrict__ hist, const float* __restrict__ Wz,
    const float* __restrict__ Wf, const float* __restrict__ emb,
    const float* __restrict__ Wv, const float* __restrict__ xbar,
    unsigned short* __restrict__ Wkb, unsigned short* __restrict__ Wqb,
    unsigned short* __restrict__ Yb, unsigned short* __restrict__ Wzb,
    unsigned short* __restrict__ Wfb, unsigned short* __restrict__ XT,
    unsigned short* __restrict__ WvT,
    float* __restrict__ u, float* __restrict__ v) {
  __shared__ float red[4];
  __shared__ float tile[32][33];
  const int b = blockIdx.x, tid = threadIdx.x;

  if (b < 16384) {                      // cvt + xbar-dot (Wk / Wq)
    const float* src = (b < 8192) ? Wk : Wq;
    unsigned short* dst = (b < 8192) ? Wkb : Wqb;
    float* dot = (b < 8192) ? u : v;
    int row = b & 8191;
    float4 x  = ((const float4*)(src + (size_t)row * EMB))[tid];
    float4 xb = ((const float4*)xbar)[tid];
    ushort4 o; o.x = f2bf(x.x); o.y = f2bf(x.y); o.z = f2bf(x.z); o.w = f2bf(x.w);
    ((ushort4*)(dst + (size_t)row * EMB))[tid] = o;
    float s = x.x * xb.x + x.y * xb.y + x.z * xb.z + x.w * xb.w;
    int lane = tid & 63, w = tid >> 6;
#pragma unroll
    for (int off = 32; off; off >>= 1) s += __shfl_down(s, off);
    if (lane == 0) red[w] = s;
    __syncthreads();
    if (tid == 0) dot[row] = red[0] + red[1] + red[2] + red[3];
  } else if (b < 29696) {               // plain row conversions
    const float* src; unsigned short* dst; int row;
    if (b < 20480)      { src = hist; dst = Yb;  row = b - 16384; }
    else if (b < 28672) { src = Wz;   dst = Wzb; row = b - 20480; }
    else                { src = Wf;   dst = Wfb; row = b - 28672; }
    float4 x = ((const float4*)(src + (size_t)row * EMB))[tid];
    ushort4 o; o.x = f2bf(x.x); o.y = f2bf(x.y); o.z = f2bf(x.z); o.w = f2bf(x.w);
    ((ushort4*)(dst + (size_t)row * EMB))[tid] = o;
  } else {                              // 32x32 transpose tiles (cols = 1024)
    const float* src; unsigned short* dst; int rows, c0, r0;
    if (b < 33792) {
      int tt = b - 29696;               // emb [4096][1024] -> XT [1024][4096]
      src = emb; dst = XT; rows = SEQ;
      c0 = (tt & 31) * 32; r0 = (tt >> 5) * 32;
    } else {
      int t2 = b - 33792;               // Wv_h [1024][1024] -> WvT_h
      int z = t2 >> 10, tt = t2 & 1023;
      src = Wv + (size_t)z * EMB * EMB; dst = WvT + (size_t)z * EMB * EMB;
      rows = EMB;
      c0 = (tt & 31) * 32; r0 = (tt >> 5) * 32;
    }
    int tx = tid & 31, ty = tid >> 5;
#pragma unroll
    for (int k = 0; k < 4; ++k) {
      int r = ty + k * 8;
      tile[r][tx] = src[(size_t)(r0 + r) * EMB + c0 + tx];
    }
    __syncthreads();
#pragma unroll
    for (int k = 0; k < 4; ++k) {
      int r = ty + k * 8;
      dst[(size_t)(c0 + r) * rows + r0 + tx] = f2bf(tile[tx][r]);
    }
  }
}

// ---------------------------------------------------------------- small vecs
__global__ __launch_bounds__(256) void colsum_part_k(const float* __restrict__ X,
                                                     float* __restrict__ part) {
  int e = blockIdx.x * 256 + threadIdx.x;  // grid.x = 4
  int y = blockIdx.y;                      // 32 chunks of 128 rows
  float s = 0.f;
  for (int r = y * 128; r < y * 128 + 128; ++r) s += X[(size_t)r * EMB + e];
  part[y * EMB + e] = s;
}
__global__ __launch_bounds__(256) void colsum_red_k(const float* __restrict__ part,
                                                    float* __restrict__ xbar) {
  int e = blockIdx.x * 256 + threadIdx.x;
  float s = 0.f;
  for (int y = 0; y < 32; ++y) s += part[y * EMB + e];
  xbar[e] = s;
}

// d[g] = bz[g] + dot(Wzb[g,:], c)  (bf16 weights, one block per g)
__global__ __launch_bounds__(256) void dvec_k(const unsigned short* __restrict__ Wzb,
                                              const float* __restrict__ bz,
                                              const float* __restrict__ c,
                                              float* __restrict__ d) {
  __shared__ float sb[4];
  int g = blockIdx.x, tid = threadIdx.x;
  const unsigned short* row = Wzb + (size_t)g * (NH * EMB);
  float s = 0.f;
#pragma unroll
  for (int p = 0; p < 4; ++p) {
    int i = p * 256 + tid;               // us8 chunk index (1024 per row)
    us8 w = ((const us8*)row)[i];
    float4 c0 = ((const float4*)c)[i * 2];
    float4 c1 = ((const float4*)c)[i * 2 + 1];
    s += bf2f(w[0]) * c0.x + bf2f(w[1]) * c0.y + bf2f(w[2]) * c0.z + bf2f(w[3]) * c0.w;
    s += bf2f(w[4]) * c1.x + bf2f(w[5]) * c1.y + bf2f(w[6]) * c1.z + bf2f(w[7]) * c1.w;
  }
  int lane = tid & 63, w = tid >> 6;
#pragma unroll
  for (int off = 32; off; off >>= 1) s += __shfl_down(s, off);
  if (lane == 0) sb[w] = s;
  __syncthreads();
  if (tid == 0) d[g] = bz[g] + sb[0] + sb[1] + sb[2] + sb[3];
}

// MT[g][e] = bf16( sum_h Mp[h][e][g] ), Mp bf16
__global__ __launch_bounds__(256) void mred_tr_k(const unsigned short* __restrict__ Mp,
                                                 unsigned short* __restrict__ MT) {
  __shared__ float t[32][33];
  int g0 = blockIdx.x * 32, e0 = blockIdx.y * 32;
  int tx = threadIdx.x & 31, ty = threadIdx.x >> 5;
#pragma unroll
  for (int k = 0; k < 4; ++k) {
    int e = e0 + ty + k * 8;
    float s = 0.f;
#pragma unroll
    for (int h = 0; h < NH; ++h)
      s += bf2f(Mp[((size_t)h << 20) + (size_t)e * EMB + g0 + tx]);
    t[ty + k * 8][tx] = s;
  }
  __syncthreads();
#pragma unroll
  for (int k = 0; k < 4; ++k) {
    int r = ty + k * 8;
    MT[(size_t)(g0 + r) * EMB + e0 + tx] = f2bf(t[tx][r]);
  }
}

// Gbf[i] = bf16( sum_z Gp[z][i] ), Gp bf16 partials
__global__ __launch_bounds__(256) void gram_red_k(const unsigned short* __restrict__ Gp,
                                                  unsigned short* __restrict__ Gbf) {
  int i = blockIdx.x * 256 + threadIdx.x;  // ushort4 index
  float4 s = {0.f, 0.f, 0.f, 0.f};
#pragma unroll
  for (int z = 0; z < 8; ++z) {
    ushort4 v = ((const ushort4*)(Gp + (size_t)z * EMB * EMB))[i];
    s.x += bf2f(v.x); s.y += bf2f(v.y); s.z += bf2f(v.z); s.w += bf2f(v.w);
  }
  ushort4 o; o.x = f2bf(s.x); o.y = f2bf(s.y); o.z = f2bf(s.z); o.w = f2bf(s.w);
  ((ushort4*)Gbf)[i] = o;
}

// ------------------------------------------- transposed-softmax pipeline
// stats1: per (colblk, rowchunk, head): online max/sum-exp over 64 rows.
__global__ __launch_bounds__(256) void colstat1_k(const float* __restrict__ ScT,
                                                  float* __restrict__ m_part,
                                                  float* __restrict__ s_part) {
  int col = blockIdx.x * 256 + threadIdx.x;   // grid.x = 4
  int rc = blockIdx.y, h = blockIdx.z;        // 16 chunks x 8 heads
  const float* base = ScT + ((size_t)h * EMB + rc * 64) * EMB + col;
  float m = -1e30f, s = 0.f;
#pragma unroll 4
  for (int r = 0; r < 64; ++r) {
    float x = base[(size_t)r * EMB];
    float nm = fmaxf(m, x);
    s = s * __expf(m - nm) + __expf(x - nm);
    m = nm;
  }
  m_part[((size_t)h * 16 + rc) * EMB + col] = m;
  s_part[((size_t)h * 16 + rc) * EMB + col] = s;
}

// stats2: merge 16 chunk-partials per column -> m_fin, 1/sum
__global__ __launch_bounds__(256) void colstat2_k(const float* __restrict__ m_part,
                                                  const float* __restrict__ s_part,
                                                  float* __restrict__ mfin,
                                                  float* __restrict__ isfin) {
  int i = blockIdx.x * 256 + threadIdx.x;     // (h,col) flat, grid = 32
  int h = i >> 10, col = i & 1023;
  float M = -1e30f, S = 0.f;
#pragma unroll
  for (int c = 0; c < 16; ++c) {
    float m = m_part[((size_t)h * 16 + c) * EMB + col];
    float s = s_part[((size_t)h * 16 + c) * EMB + col];
    float nm = fmaxf(M, m);
    S = S * __expf(M - nm) + s * __expf(m - nm);
    M = nm;
  }
  mfin[i] = M;
  isfin[i] = 1.0f / S;
}

// AT row f: AT[f][e'] = exp(ScT - m[e'])*is[e'] (bf16) + dot with bv -> cbuf
__global__ __launch_bounds__(256) void at_cvec_k(const float* __restrict__ ScT,
                                                 const float* __restrict__ mfin,
                                                 const float* __restrict__ isfin,
                                                 const float* __restrict__ bv,
                                                 unsigned short* __restrict__ AT,
                                                 float* __restrict__ cbuf) {
  __shared__ float sb[4];
  int f = blockIdx.x, h = blockIdx.y, tid = threadIdx.x;
  size_t rowoff = ((size_t)h * EMB + f) * EMB;
  float4 x  = ((const float4*)(ScT + rowoff))[tid];
  float4 m  = ((const float4*)(mfin + (size_t)h * EMB))[tid];
  float4 is = ((const float4*)(isfin + (size_t)h * EMB))[tid];
  float4 b  = ((const float4*)(bv + (size_t)h * EMB))[tid];
  float a0 = __expf(x.x - m.x) * is.x;
  float a1 = __expf(x.y - m.y) * is.y;
  float a2 = __expf(x.z - m.z) * is.z;
  float a3 = __expf(x.w - m.w) * is.w;
  ushort4 o; o.x = f2bf(a0); o.y = f2bf(a1); o.z = f2bf(a2); o.w = f2bf(a3);
  ((ushort4*)(AT + rowoff))[tid] = o;
  float s = a0 * b.x + a1 * b.y + a2 * b.z + a3 * b.w;
  int lane = tid & 63, w = tid >> 6;
#pragma unroll
  for (int off = 32; off; off >>= 1) s += __shfl_down(s, off);
  if (lane == 0) sb[w] = s;
  __syncthreads();
  if (tid == 0) cbuf[h * EMB + f] = sb[0] + sb[1] + sb[2] + sb[3];
}

// ---------------------------------------------------------------- LN
__global__ __launch_bounds__(256) void layernorm_k(const float* __restrict__ Xin,
                                                   const float* __restrict__ resid,
                                                   const float* __restrict__ gw,
                                                   const float* __restrict__ bw,
                                                   float* __restrict__ outf,
                                                   unsigned short* __restrict__ outb) {
  __shared__ float sb[16];
  int row = blockIdx.x, tid = threadIdx.x;
  float4 v = ((const float4*)(Xin + (size_t)row * EMB))[tid];
  float s = v.x + v.y + v.z + v.w;
  float q = v.x * v.x + v.y * v.y + v.z * v.z + v.w * v.w;
  int lane = tid & 63, w = tid >> 6;
#pragma unroll
  for (int off = 32; off; off >>= 1) { s += __shfl_down(s, off); q += __shfl_down(q, off); }
  if (lane == 0) { sb[w] = s; sb[8 + w] = q; }
  __syncthreads();
  float mu  = (sb[0] + sb[1] + sb[2] + sb[3]) * (1.0f / EMB);
  float var = (sb[8] + sb[9] + sb[10] + sb[11]) * (1.0f / EMB) - mu * mu;
  float rs = rsqrtf(var + 1e-5f);
  float4 rv = ((const float4*)(resid + (size_t)row * EMB))[tid];
  float4 gv = ((const float4*)gw)[tid];
  float4 bv = ((const float4*)bw)[tid];
  float o0 = (v.x - mu) * rs * gv.x + bv.x + rv.x;
  float o1 = (v.y - mu) * rs * gv.y + bv.y + rv.y;
  float o2 = (v.z - mu) * rs * gv.z + bv.z + rv.z;
  float o3 = (v.w - mu) * rs * gv.w + bv.w + rv.w;
  float4 ov; ov.x = o0; ov.y = o1; ov.z = o2; ov.w = o3;
  ((float4*)(outf + (size_t)row * EMB))[tid] = ov;
  if (outb) {
    ushort4 ob; ob.x = f2bf(o0); ob.y = f2bf(o1); ob.z = f2bf(o2); ob.w = f2bf(o3);
    ((ushort4*)(outb + (size_t)row * EMB))[tid] = ob;
  }
}

// ---------------------------------------------------------------- GEMM (NT)
// C[m,n] = sum_k A[m*lda+k] * B[n*ldb+k], bf16 in, f32 acc.
// MODE 0: f32 store. 1: bf16 store. 3: +bias[n], f32. 4: scoresT epilogue.
template <int MODE>
__global__ __launch_bounds__(256) void gemm_nt(const unsigned short* __restrict__ A,
                                               const unsigned short* __restrict__ B,
                                               void* __restrict__ Cout,
                                               int K, int lda, int ldb, int ldc,
                                               long long aZ, long long bZ, long long cZ,
                                               const float* __restrict__ e0,
                                               const float* __restrict__ e1,
                                               const float* __restrict__ e2,
                                               const float* __restrict__ e3) {
  const int z = blockIdx.z;
  A += (size_t)z * aZ;
  B += (size_t)z * bZ;
  const int tid = threadIdx.x;
  const int lane = tid & 63, wid = tid >> 6;
  const int wm = wid >> 1, wn = wid & 1;
  const int row0 = blockIdx.x * 128, col0 = blockIdx.y * 128;

  __shared__ __align__(16) unsigned short As[2][128 * 64];
  __shared__ __align__(16) unsigned short Bs[2][128 * 64];

  f32x4 acc[4][4] = {};
  const int lrow = lane & 15, kg = lane >> 4;
  const int lr = lane >> 3;        // row within an 8-row chunk
  const int lc = (lane & 7) * 8;   // elem col within 64

  auto stage = [&](int buf, int k0) {
#pragma unroll
    for (int c = 0; c < 4; ++c) {
      int chunk = wid * 4 + c;           // 0..15, 8 rows each
      int r = chunk * 8 + lr;
      GLOAD_LDS16(A + (size_t)(row0 + r) * lda + k0 + lc, &As[buf][chunk * 512]);
      GLOAD_LDS16(B + (size_t)(col0 + r) * ldb + k0 + lc, &Bs[buf][chunk * 512]);
    }
  };

  stage(0, 0);
  __syncthreads();

  const int nt = K >> 6;
  for (int t = 0; t < nt; ++t) {
    const int cur = t & 1;
    if (t + 1 < nt) stage(cur ^ 1, (t + 1) << 6);
#pragma unroll
    for (int ks = 0; ks < 2; ++ks) {
      bf16x8 a[4], b[4];
      int koff = ks * 32 + kg * 8;
#pragma unroll
      for (int i = 0; i < 4; ++i)
        a[i] = *(const bf16x8*)&As[cur][(wm * 64 + i * 16 + lrow) * 64 + koff];
#pragma unroll
      for (int j = 0; j < 4; ++j)
        b[j] = *(const bf16x8*)&Bs[cur][(wn * 64 + j * 16 + lrow) * 64 + koff];
#pragma unroll
      for (int i = 0; i < 4; ++i)
#pragma unroll
        for (int j = 0; j < 4; ++j)
          acc[i][j] = __builtin_amdgcn_mfma_f32_16x16x32_bf16(a[i], b[j], acc[i][j], 0, 0, 0);
    }
    __syncthreads();
  }

  const int rb = (lane >> 4) * 4, cc = lane & 15;
#pragma unroll
  for (int i = 0; i < 4; ++i) {
#pragma unroll
    for (int j = 0; j < 4; ++j) {
#pragma unroll
      for (int r = 0; r < 4; ++r) {
        int m = row0 + wm * 64 + i * 16 + rb + r;
        int n = col0 + wn * 64 + j * 16 + cc;
        float val = acc[i][j][r];
        size_t off = (size_t)z * cZ + (size_t)m * ldc + n;
        if (MODE == 0) {
          ((float*)Cout)[off] = val;
        } else if (MODE == 1) {
          ((unsigned short*)Cout)[off] = f2bf(val);
        } else if (MODE == 3) {
          ((float*)Cout)[off] = val + e0[n];
        } else if (MODE == 4) {
          // scoresT = (val + bq[m]*(u[n] + S*bk[n]) + v[m]*bk[n]) / 32
          float bq = e0[z * EMB + m], uu = e1[z * EMB + n];
          float bk = e2[z * EMB + n], vv = e3[z * EMB + m];
          ((float*)Cout)[off] = (val + bq * (uu + (float)SEQ * bk) + vv * bk) * (1.0f / 32.0f);
        }
      }
    }
  }
}

// ---------------------------------------------------------------- launch
extern "C" void kernel_launch(void* const* d_in, const int* in_sizes, int n_in,
                              void* d_out, int out_size, void* d_ws, size_t ws_size,
                              hipStream_t stream) {
  const float* history = (const float*)d_in[0];
  const float* emb     = (const float*)d_in[1];
  const float* Wq_w = (const float*)d_in[2];
  const float* Wq_b = (const float*)d_in[3];
  const float* Wk_w = (const float*)d_in[4];
  const float* Wk_b = (const float*)d_in[5];
  const float* Wv_w = (const float*)d_in[6];
  const float* Wv_b = (const float*)d_in[7];
  const float* Wz_w = (const float*)d_in[8];
  const float* Wz_b = (const float*)d_in[9];
  const float* ln1_g = (const float*)d_in[10];
  const float* ln1_b = (const float*)d_in[11];
  const float* Wf_w = (const float*)d_in[12];
  const float* Wf_b = (const float*)d_in[13];
  const float* ln2_g = (const float*)d_in[14];
  const float* ln2_b = (const float*)d_in[15];

  char* ws = (char*)d_ws;
  const size_t MB = 1024ull * 1024ull;
  unsigned short* XT  = (unsigned short*)(ws + 0);        // [E][S] bf16, 8MB ; later LN1bf
  unsigned short* Ybf = (unsigned short*)(ws + 8 * MB);   // [S][E] bf16, 8MB
  unsigned short* Wkb = (unsigned short*)(ws + 16 * MB);  // [H][E][E] bf16, 16MB
  unsigned short* Wqb = (unsigned short*)(ws + 32 * MB);
  unsigned short* WvT = (unsigned short*)(ws + 48 * MB);  // [H][E'][E] transposed
  unsigned short* Wzb = (unsigned short*)(ws + 64 * MB);  // [E][H*E]
  unsigned short* Wfb = (unsigned short*)(ws + 80 * MB);  // [E][E], 2MB
  unsigned short* Gbf = (unsigned short*)(ws + 82 * MB);  // [E][E] bf16 (symmetric), 2MB
  float* xpart = (float*)(ws + 84 * MB);                  // 128 KB
  float* xbar  = (float*)(ws + 84 * MB + 160 * 1024);     // 4 KB
  float* ubuf  = (float*)(ws + 84 * MB + 192 * 1024);     // [H][E] 32 KB
  float* vbuf  = (float*)(ws + 84 * MB + 256 * 1024);
  float* cbuf  = (float*)(ws + 84 * MB + 320 * 1024);     // [H][E]
  float* dbuf  = (float*)(ws + 84 * MB + 384 * 1024);     // [E]
  unsigned short* Tbf = (unsigned short*)(ws + 85 * MB);  // 16MB; later Cbf, later FN f32
  float* Sc  = (float*)(ws + 101 * MB);                   // 32MB: Gp(bf16), scoresT f32, Mp(bf16)
  char*  St  = ws + 133 * MB;                             // stats; later O f32
  unsigned short* ATb = (unsigned short*)(ws + 149 * MB); // 16MB; later LN1 f32
  unsigned short* MTb = (unsigned short*)(ws + 165 * MB); // 2MB
  // stats area (consumed before O GEMM overwrites it)
  float* m_part = (float*)(St);                  // 512 KB [H][16][E]
  float* s_part = (float*)(St + 512 * 1024);     // 512 KB
  float* mfin   = (float*)(St + 1024 * 1024);    // 32 KB [H][E]
  float* isfin  = (float*)(St + 1056 * 1024);    // 32 KB
  // aliases (lifetimes verified non-overlapping)
  unsigned short* Gp = (unsigned short*)Sc;  // [8][E][E] bf16 Gram partials
  unsigned short* Cbf  = Tbf;
  unsigned short* Mp = (unsigned short*)Sc;  // [H][E][E] bf16 after scoresT consumed
  float* Obuf = (float*)St;
  float* LN1  = (float*)ATb;
  unsigned short* LN1b = XT;
  float* FN   = (float*)Tbf;

  // --- xbar (needed by mega-cvt's fused dot)
  colsum_part_k<<<dim3(4, 32), 256, 0, stream>>>(emb, xpart);
  colsum_red_k<<<dim3(4), 256, 0, stream>>>(xpart, xbar);

  // --- all conversions/transposes in one dispatch
  mega_cvt_k<<<dim3(41984), 256, 0, stream>>>(Wk_w, Wq_w, history, Wz_w, Wf_w,
                                              emb, Wv_w, xbar,
                                              Wkb, Wqb, Ybf, Wzb, Wfb, XT, WvT,
                                              ubuf, vbuf);

  // --- G = XT * XT^T, split-K over z (8 x K=512) -> bf16 partials -> bf16
  gemm_nt<1><<<dim3(8, 8, 8), 256, 0, stream>>>(XT, XT, Gp, 512, SEQ, SEQ, EMB,
                                                512, 512, (long long)EMB * EMB,
                                                nullptr, nullptr, nullptr, nullptr);
  gram_red_k<<<dim3(EMB * EMB / 4 / 256), 256, 0, stream>>>(Gp, Gbf);
  // --- T2_h = Wq_h * G  (G symmetric; NT B-operand)
  gemm_nt<1><<<dim3(8, 8, NH), 256, 0, stream>>>(Wqb, Gbf, Tbf, EMB, EMB, EMB, EMB,
                                                 (long long)EMB * EMB, 0, (long long)EMB * EMB,
                                                 nullptr, nullptr, nullptr, nullptr);
  // --- scoresT_h = T2_h * Wk_h^T / 32 + rank-1 bias terms
  gemm_nt<4><<<dim3(8, 8, NH), 256, 0, stream>>>(Tbf, Wkb, Sc, EMB, EMB, EMB, EMB,
                                                 (long long)EMB * EMB, (long long)EMB * EMB,
                                                 (long long)EMB * EMB, Wq_b, ubuf, Wk_b, vbuf);
  // --- column softmax stats of scoresT (softmax dim = rows of scoresT)
  colstat1_k<<<dim3(4, 16, NH), 256, 0, stream>>>(Sc, m_part, s_part);
  colstat2_k<<<dim3(32), 256, 0, stream>>>(m_part, s_part, mfin, isfin);
  // --- AT = exp(scoresT - m)*is (bf16) fused with cvec dot
  at_cvec_k<<<dim3(EMB, NH), 256, 0, stream>>>(Sc, mfin, isfin, Wv_b, ATb, cbuf);
  // --- C_h = WvT_h * AT_h^T  == Wv_h^T A_h
  gemm_nt<1><<<dim3(8, 8, NH), 256, 0, stream>>>(WvT, ATb, Cbf, EMB, EMB, EMB, EMB,
                                                 (long long)EMB * EMB, (long long)EMB * EMB,
                                                 (long long)EMB * EMB,
                                                 nullptr, nullptr, nullptr, nullptr);
  // --- Mp_h = C_h * Wz_h^T  (bf16 partials)
  gemm_nt<1><<<dim3(8, 8, NH), 256, 0, stream>>>(Cbf, Wzb, Mp, EMB, EMB, NH * EMB, EMB,
                                                 (long long)EMB * EMB, (long long)EMB,
                                                 (long long)EMB * EMB,
                                                 nullptr, nullptr, nullptr, nullptr);
  // --- M = sum_h Mp_h, transposed+bf16 ; d vector
  mred_tr_k<<<dim3(EMB / 32, EMB / 32), 256, 0, stream>>>(Mp, MTb);
  dvec_k<<<dim3(EMB), 256, 0, stream>>>(Wzb, Wz_b, cbuf, dbuf);
  // --- O = Y * M + d
  gemm_nt<3><<<dim3(SEQ / 128, 8, 1), 256, 0, stream>>>(Ybf, MTb, Obuf, EMB, EMB, EMB, EMB,
                                                        0, 0, 0, dbuf, nullptr, nullptr, nullptr);
  // --- LN1 = LN(O)+emb (f32 + bf16 copies)
  layernorm_k<<<dim3(SEQ), 256, 0, stream>>>(Obuf, emb, ln1_g, ln1_b, LN1, LN1b);
  // --- FN = LN1 * Wf^T + bf
  gemm_nt<3><<<dim3(SEQ / 128, 8, 1), 256, 0, stream>>>(LN1b, Wfb, FN, EMB, EMB, EMB, EMB,
                                                        0, 0, 0, Wf_b, nullptr, nullptr, nullptr);
  // --- out = LN(FN)+LN1
  layernorm_k<<<dim3(SEQ), 256, 0, stream>>>(FN, LN1, ln2_g, ln2_b, (float*)d_out, nullptr);
}